// Round 12
// baseline (390.996 us; speedup 1.0000x reference)
//
#include <hip/hip_runtime.h>
#include <hip/hip_bf16.h>

#define TT 8
#define NN 50000
#define FF 128
#define HH 64
#define CC 4
#define EE 800000
#define NB2 391           // buckets of 128 nodes (ceil(50000/128))
#define CAP 2560          // padded records per (t,bucket): mean 2048, sd ~45 -> 11 sigma
#define BPT 64            // multisplit blocks per timestep

typedef unsigned short u16;
typedef unsigned int u32;
typedef __attribute__((ext_vector_type(8))) short bf16x8;
typedef __attribute__((ext_vector_type(4))) float f32x4;

static __device__ __forceinline__ float bflo(u32 w) {
    union { unsigned int i; float f; } v; v.i = w << 16; return v.f;
}
static __device__ __forceinline__ float bfhi(u32 w) {
    union { unsigned int i; float f; } v; v.i = w & 0xFFFF0000u; return v.f;
}
static __device__ __forceinline__ u16 cvt_bf16(float f) {
    __hip_bfloat16 b = __float2bfloat16(f);          // native RNE (v_cvt_pk-able)
    return *reinterpret_cast<u16*>(&b);
}

// ---------------- multisplit: edges -> 64B-aligned padded bucket windows ----------------
// LDS line buffers; only full aligned 64B lines flushed. 512 edges staged per flush round.
__global__ __launch_bounds__(256) void multisplit_kernel(const int* __restrict__ edges,
                                                         int* __restrict__ gcur, u32* __restrict__ binned) {
    __shared__ u32 sbuf[NB2][16];
    __shared__ int scnt[NB2];
    int bid = blockIdx.x;
    int t = bid & 7;
    int blk = bid >> 3;                       // 0..BPT-1
    const int per = (EE + BPT - 1) / BPT;     // 12500
    int e0 = blk * per;
    int e1 = e0 + per; if (e1 > EE) e1 = EE;

    for (int i = threadIdx.x; i < NB2; i += 256) scnt[i] = 0;
    __syncthreads();

    const int* es = edges + (size_t)(t * 2 + 0) * EE;
    const int* ed = edges + (size_t)(t * 2 + 1) * EE;
    int* gc = gcur + t * NB2;
    u32* bb = binned + (size_t)t * NB2 * CAP;

    for (int base = e0; base < e1; base += 512) {
        u32 recA = 0, recB = 0; int bA = -1, bB = -1;
        int eA = base + threadIdx.x;
        int eB = base + 256 + threadIdx.x;
        if (eA < e1) {
            int src = es[eA], dst = ed[eA];
            bA = dst >> 7;
            recA = (u32)src | ((u32)(dst & 127) << 16);
            int p = atomicAdd(&scnt[bA], 1);
            if (p < 16) { sbuf[bA][p] = recA; bA = -1; }
        }
        if (eB < e1) {
            int src = es[eB], dst = ed[eB];
            bB = dst >> 7;
            recB = (u32)src | ((u32)(dst & 127) << 16);
            int p = atomicAdd(&scnt[bB], 1);
            if (p < 16) { sbuf[bB][p] = recB; bB = -1; }
        }
        __syncthreads();
        // flush any full 64B line
        for (int fb = threadIdx.x; fb < NB2; fb += 256) {
            if (scnt[fb] >= 16) {
                int g = atomicAdd(&gc[fb], 16);
                uint4* dp = (uint4*)(bb + (size_t)fb * CAP + g);
                uint4* sp = (uint4*)&sbuf[fb][0];
                dp[0] = sp[0]; dp[1] = sp[1]; dp[2] = sp[2]; dp[3] = sp[3];
                scnt[fb] = 0;                            // pendings re-append below
            }
        }
        __syncthreads();
        if (bA >= 0) {                                   // pending retry (count was >16)
            int p = atomicAdd(&scnt[bA], 1);
            if (p < 16) sbuf[bA][p] = recA;
            else { int g = atomicAdd(&gc[bA], 1); bb[(size_t)bA * CAP + g] = recA; }  // ultra-rare
        }
        if (bB >= 0) {
            int p = atomicAdd(&scnt[bB], 1);
            if (p < 16) sbuf[bB][p] = recB;
            else { int g = atomicAdd(&gc[bB], 1); bb[(size_t)bB * CAP + g] = recB; }
        }
        __syncthreads();
    }
    // residual (<16 per bucket) partial flush
    for (int fb = threadIdx.x; fb < NB2; fb += 256) {
        int c = scnt[fb];
        if (c > 0) {
            int g = atomicAdd(&gc[fb], c);
            for (int k = 0; k < c; ++k) bb[(size_t)fb * CAP + g + k] = sbuf[fb][k];
        }
    }
}

// ---------------- per-bucket: local degree hist + scan -> CSR scatter + nodeinfo + dinv ----------------
__global__ __launch_bounds__(256) void csr_scatter_kernel(const u32* __restrict__ binned, const int* __restrict__ gcur,
                                                          u16* __restrict__ srclist, u32* __restrict__ nodeinfo,
                                                          float* __restrict__ dinv) {
    __shared__ u32 recs[CAP];
    __shared__ int hist[128];
    __shared__ int cur[128];
    int b = blockIdx.x, t = blockIdx.y, tid = threadIdx.x;
    int node0 = b * 128;
    int tot = gcur[t * NB2 + b];
    const u32* win = binned + ((size_t)t * NB2 + b) * CAP;

    for (int i = tid; i < tot; i += 256) recs[i] = win[i];
    if (tid < 128) hist[tid] = 0;
    __syncthreads();
    for (int i = tid; i < tot; i += 256) atomicAdd(&hist[recs[i] >> 16], 1);
    __syncthreads();
    int h = 0;
    if (tid < 128) h = hist[tid];
    for (int off = 1; off < 128; off <<= 1) {
        int v = 0;
        if (tid < 128 && tid >= off) v = hist[tid - off];
        __syncthreads();
        if (tid < 128) hist[tid] += v;
        __syncthreads();
    }
    if (tid < 128) {
        int excl = hist[tid] - h;
        cur[tid] = excl;
        int node = node0 + tid;
        if (node < NN) {
            nodeinfo[t * NN + node] = (u32)(b * CAP + excl) | ((u32)h << 20);
            dinv[t * NN + node] = rsqrtf(1.0f + (float)h);
        }
    }
    __syncthreads();
    u16* sl = srclist + (size_t)t * NB2 * CAP;
    for (int i = tid; i < tot; i += 256) {
        u32 rec = recs[i];
        int d = rec >> 16;
        int p = atomicAdd(&cur[d], 1);
        sl[(size_t)b * CAP + p] = (u16)(rec & 0xFFFF);
    }
}

// ---------------- W transpose + bf16 convert (once per t) ----------------
__global__ __launch_bounds__(256) void wt_prep_kernel(const float* __restrict__ Wg, u16* __restrict__ wt) {
    int t = blockIdx.x;
    const float* w = Wg + t * FF * HH;
    u16* o = wt + (size_t)t * HH * FF;
    for (int i = threadIdx.x; i < FF * HH; i += 256) {
        int k = i >> 6, c = i & 63;
        o[c * FF + k] = cvt_bf16(w[i]);
    }
}

// ---------------- y = (x @ Wg) * dinv via bf16 MFMA, no LDS (direct reg loads) ----------------
// A: two float4 from x per k0, packed to bf16 with NATIVE v_cvt_pk_bf16_f32 (the hand-rolled
// round-shift f2bf was ~4 VALU ops/elem -> 64 ops per k0 vs 4 MFMAs: conversion-VALU-bound).
__global__ __launch_bounds__(256) void xw_kernel(const float* __restrict__ x, const u16* __restrict__ wt,
                                                 const float* __restrict__ dinv, u16* __restrict__ y) {
    int t = blockIdx.y;
    int row0 = blockIdx.x * 64;
    int tid = threadIdx.x;
    int w = tid >> 6, lane = tid & 63;
    int wr = w * 16;
    int l15 = lane & 15, lg = lane >> 4;
    int arow = row0 + wr + l15;
    const float* xt = x + (size_t)t * NN * FF;
    const u16* wtt = wt + (size_t)t * HH * FF;

    f32x4 d[4] = {{0,0,0,0},{0,0,0,0},{0,0,0,0},{0,0,0,0}};
    #pragma unroll
    for (int k0 = 0; k0 < 128; k0 += 32) {
        int kb = k0 + lg * 8;
        union { bf16x8 v; __hip_bfloat162 h[4]; } au;
        if (arow < NN) {
            float4 f0 = *reinterpret_cast<const float4*>(&xt[(size_t)arow * FF + kb]);
            float4 f1 = *reinterpret_cast<const float4*>(&xt[(size_t)arow * FF + kb + 4]);
            au.h[0] = __float22bfloat162_rn(make_float2(f0.x, f0.y));
            au.h[1] = __float22bfloat162_rn(make_float2(f0.z, f0.w));
            au.h[2] = __float22bfloat162_rn(make_float2(f1.x, f1.y));
            au.h[3] = __float22bfloat162_rn(make_float2(f1.z, f1.w));
        } else {
            au.v = (bf16x8){0,0,0,0,0,0,0,0};
        }
        #pragma unroll
        for (int n = 0; n < 4; ++n) {
            bf16x8 bf = *reinterpret_cast<const bf16x8*>(&wtt[(size_t)(n * 16 + l15) * FF + kb]);
            d[n] = __builtin_amdgcn_mfma_f32_16x16x32_bf16(au.v, bf, d[n], 0, 0, 0);
        }
    }
    // epilogue: * dinv -> bf16 row-major [N][64]
    int rbase = row0 + wr + lg * 4;
    float dv[4];
    #pragma unroll
    for (int i = 0; i < 4; ++i) {
        int grow = rbase + i;
        dv[i] = (grow < NN) ? dinv[t * NN + grow] : 0.f;
    }
    u16* yt = y + (size_t)t * NN * HH;
    #pragma unroll
    for (int n = 0; n < 4; ++n) {
        int col = n * 16 + l15;
        #pragma unroll
        for (int i = 0; i < 4; ++i) {
            int grow = rbase + i;
            if (grow < NN) yt[(size_t)grow * HH + col] = cvt_bf16(d[n][i] * dv[i]);
        }
    }
}

// ---------------- gather-aggregate over all T (single pass, full 128B rows) ----------------
// EXACT r8 structure (best measured: 177us @ 401MB compulsory floor, 2.3TB/s).
__global__ __launch_bounds__(256) void agg_kernel(const u16* __restrict__ y, const float* __restrict__ dinv,
                                                  const u32* __restrict__ nodeinfo, const u16* __restrict__ srclist,
                                                  const float* __restrict__ bg, float* __restrict__ acc) {
    int node = blockIdx.x * 4 + (threadIdx.x >> 6);
    int lane = threadIdx.x & 63;
    int sub = lane >> 4;            // edge slot 0..3
    int fo = lane & 15;             // feature quad: feats fo*4 .. fo*4+3
    float a0 = 0.f, a1 = 0.f, a2 = 0.f, a3 = 0.f;
    for (int t = 0; t < TT; ++t) {
        const u16* yt = y + (size_t)t * NN * HH;
        u32 info = nodeinfo[t * NN + node];
        int cnt = info >> 20;
        const u16* sl = srclist + (size_t)t * NB2 * CAP + (info & 0xFFFFF);
        float s0 = 0.f, s1 = 0.f, s2 = 0.f, s3 = 0.f;
        int j = 0;
        for (; j + 16 <= cnt; j += 16) {
            int e0 = sl[j + sub], e1 = sl[j + 4 + sub], e2 = sl[j + 8 + sub], e3 = sl[j + 12 + sub];
            uint2 v0 = *reinterpret_cast<const uint2*>(&yt[(size_t)e0 * HH + fo * 4]);
            uint2 v1 = *reinterpret_cast<const uint2*>(&yt[(size_t)e1 * HH + fo * 4]);
            uint2 v2 = *reinterpret_cast<const uint2*>(&yt[(size_t)e2 * HH + fo * 4]);
            uint2 v3 = *reinterpret_cast<const uint2*>(&yt[(size_t)e3 * HH + fo * 4]);
            s0 += (bflo(v0.x) + bflo(v1.x)) + (bflo(v2.x) + bflo(v3.x));
            s1 += (bfhi(v0.x) + bfhi(v1.x)) + (bfhi(v2.x) + bfhi(v3.x));
            s2 += (bflo(v0.y) + bflo(v1.y)) + (bflo(v2.y) + bflo(v3.y));
            s3 += (bfhi(v0.y) + bfhi(v1.y)) + (bfhi(v2.y) + bfhi(v3.y));
        }
        for (; j < cnt; j += 4) {
            int e = j + sub;
            uint2 v = make_uint2(0u, 0u);
            if (e < cnt) {
                int srcid = sl[e];
                v = *reinterpret_cast<const uint2*>(&yt[(size_t)srcid * HH + fo * 4]);
            }
            s0 += bflo(v.x);
            s1 += bfhi(v.x);
            s2 += bflo(v.y);
            s3 += bfhi(v.y);
        }
        s0 += __shfl_xor(s0, 16, 64); s0 += __shfl_xor(s0, 32, 64);
        s1 += __shfl_xor(s1, 16, 64); s1 += __shfl_xor(s1, 32, 64);
        s2 += __shfl_xor(s2, 16, 64); s2 += __shfl_xor(s2, 32, 64);
        s3 += __shfl_xor(s3, 16, 64); s3 += __shfl_xor(s3, 32, 64);
        // self loop (y already scaled by src dinv)
        uint2 sv = *reinterpret_cast<const uint2*>(&yt[(size_t)node * HH + fo * 4]);
        s0 += bflo(sv.x);
        s1 += bfhi(sv.x);
        s2 += bflo(sv.y);
        s3 += bfhi(sv.y);
        float dvv = dinv[t * NN + node];
        float4 bgv = *reinterpret_cast<const float4*>(&bg[t * HH + fo * 4]);
        a0 += fmaxf(dvv * s0 + bgv.x, 0.f);
        a1 += fmaxf(dvv * s1 + bgv.y, 0.f);
        a2 += fmaxf(dvv * s2 + bgv.z, 0.f);
        a3 += fmaxf(dvv * s3 + bgv.w, 0.f);
    }
    if (sub == 0) {
        float4 o = make_float4(a0, a1, a2, a3);
        *reinterpret_cast<float4*>(&acc[(size_t)node * HH + fo * 4]) = o;
    }
}

// ---------------- per-node MLP head + log_softmax ----------------
__global__ __launch_bounds__(256) void head_kernel(const float* __restrict__ acc,
                                                   const float* __restrict__ W1, const float* __restrict__ b1,
                                                   const float* __restrict__ W2, const float* __restrict__ b2,
                                                   const float* __restrict__ W3, const float* __restrict__ b3,
                                                   float* __restrict__ out) {
    __shared__ float w1[64 * 32], w2[32 * 16], w3[16 * 4], bb1[32], bb2[16], bb3[4];
    int tid = threadIdx.x;
    for (int i = tid; i < 2048; i += 256) w1[i] = W1[i];
    for (int i = tid; i < 512; i += 256) w2[i] = W2[i];
    if (tid < 64) w3[tid] = W3[tid];
    if (tid < 32) bb1[tid] = b1[tid];
    if (tid < 16) bb2[tid] = b2[tid];
    if (tid < 4) bb3[tid] = b3[tid];
    __syncthreads();
    int node = blockIdx.x * 256 + tid;
    if (node >= NN) return;

    float a[64];
    #pragma unroll
    for (int k = 0; k < 64; ++k) a[k] = acc[(size_t)node * HH + k];

    float h1[32];
    for (int j = 0; j < 32; ++j) {
        float s = bb1[j];
        #pragma unroll
        for (int k = 0; k < 64; ++k) s += a[k] * w1[k * 32 + j];
        h1[j] = fmaxf(s, 0.f);
    }
    float h2[16];
    for (int j = 0; j < 16; ++j) {
        float s = bb2[j];
        #pragma unroll
        for (int k = 0; k < 32; ++k) s += h1[k] * w2[k * 16 + j];
        h2[j] = fmaxf(s, 0.f);
    }
    float l[4];
    for (int c = 0; c < 4; ++c) {
        float s = bb3[c];
        #pragma unroll
        for (int k = 0; k < 16; ++k) s += h2[k] * w3[k * 4 + c];
        l[c] = s;
    }
    float m = fmaxf(fmaxf(l[0], l[1]), fmaxf(l[2], l[3]));
    float sum = 0.f;
    #pragma unroll
    for (int c = 0; c < 4; ++c) sum += expf(l[c] - m);
    float lse = logf(sum);
    float4 o;
    o.x = l[0] - m - lse; o.y = l[1] - m - lse; o.z = l[2] - m - lse; o.w = l[3] - m - lse;
    *reinterpret_cast<float4*>(&out[(size_t)node * CC]) = o;
}

extern "C" void kernel_launch(void* const* d_in, const int* in_sizes, int n_in,
                              void* d_out, int out_size, void* d_ws, size_t ws_size,
                              hipStream_t stream) {
    const float* x    = (const float*)d_in[0];
    const int*  edges = (const int*)d_in[1];
    const float* Wg   = (const float*)d_in[2];
    const float* bg   = (const float*)d_in[3];
    const float* W1   = (const float*)d_in[4];
    const float* b1   = (const float*)d_in[5];
    const float* W2   = (const float*)d_in[6];
    const float* b2   = (const float*)d_in[7];
    const float* W3   = (const float*)d_in[8];
    const float* b3   = (const float*)d_in[9];
    float* out = (float*)d_out;

    char* ws = (char*)d_ws;
    size_t o = 0;
    int* gcur      = (int*)(ws + o); o += (size_t)TT * NB2 * 4;            // 12.5 KB
    o = (o + 255) & ~(size_t)255;
    float* dinv    = (float*)(ws + o); o += (size_t)TT * NN * 4;           // 1.6 MB
    u32* nodeinfo  = (u32*)(ws + o); o += (size_t)TT * NN * 4;             // 1.6 MB
    o = (o + 255) & ~(size_t)255;
    u16* wt        = (u16*)(ws + o); o += (size_t)TT * HH * FF * 2;        // 128 KB
    o = (o + 255) & ~(size_t)255;
    u32* binned    = (u32*)(ws + o); o += (size_t)TT * NB2 * CAP * 4;      // 32.0 MB
    u16* srclist   = (u16*)(ws + o); o += (size_t)TT * NB2 * CAP * 2;      // 16.0 MB
    u16* y         = (u16*)(ws + o); o += (size_t)TT * NN * HH * 2;        // 51.2 MB
    float* acc     = (float*)(ws + o); o += (size_t)NN * HH * 4;           // 12.8 MB
    // total ~115 MB

    hipMemsetAsync(gcur, 0, (size_t)TT * NB2 * 4, stream);

    multisplit_kernel<<<BPT * TT, 256, 0, stream>>>(edges, gcur, binned);

    dim3 gsc(NB2, TT);
    csr_scatter_kernel<<<gsc, 256, 0, stream>>>(binned, gcur, srclist, nodeinfo, dinv);

    wt_prep_kernel<<<TT, 256, 0, stream>>>(Wg, wt);

    dim3 gx(782, TT);
    xw_kernel<<<gx, 256, 0, stream>>>(x, wt, dinv, y);

    agg_kernel<<<12500, 256, 0, stream>>>(y, dinv, nodeinfo, srclist, bg, acc);

    head_kernel<<<196, 256, 0, stream>>>(acc, W1, b1, W2, b2, W3, b3, out);
}

// Round 13
// 366.877 us; speedup vs baseline: 1.0657x; 1.0657x over previous
//
#include <hip/hip_runtime.h>
#include <hip/hip_bf16.h>

#define TT 8
#define NN 50000
#define FF 128
#define HH 64
#define CC 4
#define EE 800000
#define NB2 391           // buckets of 128 nodes (ceil(50000/128))
#define CAP 2560          // padded records per (t,bucket): mean 2048, sd ~45 -> 11 sigma
#define BPT 64            // multisplit blocks per timestep

typedef unsigned short u16;
typedef unsigned int u32;
typedef __attribute__((ext_vector_type(8))) short bf16x8;
typedef __attribute__((ext_vector_type(4))) float f32x4;

static __device__ __forceinline__ float bflo(u32 w) {
    union { unsigned int i; float f; } v; v.i = w << 16; return v.f;
}
static __device__ __forceinline__ float bfhi(u32 w) {
    union { unsigned int i; float f; } v; v.i = w & 0xFFFF0000u; return v.f;
}
static __device__ __forceinline__ u16 cvt_bf16(float f) {
    __hip_bfloat16 b = __float2bfloat16(f);          // native RNE
    return *reinterpret_cast<u16*>(&b);
}

// ---------------- multisplit: edges -> 64B-aligned padded bucket windows ----------------
__global__ __launch_bounds__(256) void multisplit_kernel(const int* __restrict__ edges,
                                                         int* __restrict__ gcur, u32* __restrict__ binned) {
    __shared__ u32 sbuf[NB2][16];
    __shared__ int scnt[NB2];
    int bid = blockIdx.x;
    int t = bid & 7;
    int blk = bid >> 3;                       // 0..BPT-1
    const int per = (EE + BPT - 1) / BPT;     // 12500
    int e0 = blk * per;
    int e1 = e0 + per; if (e1 > EE) e1 = EE;

    for (int i = threadIdx.x; i < NB2; i += 256) scnt[i] = 0;
    __syncthreads();

    const int* es = edges + (size_t)(t * 2 + 0) * EE;
    const int* ed = edges + (size_t)(t * 2 + 1) * EE;
    int* gc = gcur + t * NB2;
    u32* bb = binned + (size_t)t * NB2 * CAP;

    for (int base = e0; base < e1; base += 512) {
        u32 recA = 0, recB = 0; int bA = -1, bB = -1;
        int eA = base + threadIdx.x;
        int eB = base + 256 + threadIdx.x;
        if (eA < e1) {
            int src = es[eA], dst = ed[eA];
            bA = dst >> 7;
            recA = (u32)src | ((u32)(dst & 127) << 16);
            int p = atomicAdd(&scnt[bA], 1);
            if (p < 16) { sbuf[bA][p] = recA; bA = -1; }
        }
        if (eB < e1) {
            int src = es[eB], dst = ed[eB];
            bB = dst >> 7;
            recB = (u32)src | ((u32)(dst & 127) << 16);
            int p = atomicAdd(&scnt[bB], 1);
            if (p < 16) { sbuf[bB][p] = recB; bB = -1; }
        }
        __syncthreads();
        // flush any full 64B line
        for (int fb = threadIdx.x; fb < NB2; fb += 256) {
            if (scnt[fb] >= 16) {
                int g = atomicAdd(&gc[fb], 16);
                uint4* dp = (uint4*)(bb + (size_t)fb * CAP + g);
                uint4* sp = (uint4*)&sbuf[fb][0];
                dp[0] = sp[0]; dp[1] = sp[1]; dp[2] = sp[2]; dp[3] = sp[3];
                scnt[fb] = 0;                            // pendings re-append below
            }
        }
        __syncthreads();
        if (bA >= 0) {                                   // pending retry (count was >16)
            int p = atomicAdd(&scnt[bA], 1);
            if (p < 16) sbuf[bA][p] = recA;
            else { int g = atomicAdd(&gc[bA], 1); bb[(size_t)bA * CAP + g] = recA; }  // ultra-rare
        }
        if (bB >= 0) {
            int p = atomicAdd(&scnt[bB], 1);
            if (p < 16) sbuf[bB][p] = recB;
            else { int g = atomicAdd(&gc[bB], 1); bb[(size_t)bB * CAP + g] = recB; }
        }
        __syncthreads();
    }
    // residual (<16 per bucket) partial flush
    for (int fb = threadIdx.x; fb < NB2; fb += 256) {
        int c = scnt[fb];
        if (c > 0) {
            int g = atomicAdd(&gc[fb], c);
            for (int k = 0; k < c; ++k) bb[(size_t)fb * CAP + g + k] = sbuf[fb][k];
        }
    }
}

// ---------------- per-bucket: local degree hist + scan -> CSR scatter + nodeinfo + dinv ----------------
__global__ __launch_bounds__(256) void csr_scatter_kernel(const u32* __restrict__ binned, const int* __restrict__ gcur,
                                                          u16* __restrict__ srclist, u32* __restrict__ nodeinfo,
                                                          float* __restrict__ dinv) {
    __shared__ u32 recs[CAP];
    __shared__ int hist[128];
    __shared__ int cur[128];
    int b = blockIdx.x, t = blockIdx.y, tid = threadIdx.x;
    int node0 = b * 128;
    int tot = gcur[t * NB2 + b];
    const u32* win = binned + ((size_t)t * NB2 + b) * CAP;

    for (int i = tid; i < tot; i += 256) recs[i] = win[i];
    if (tid < 128) hist[tid] = 0;
    __syncthreads();
    for (int i = tid; i < tot; i += 256) atomicAdd(&hist[recs[i] >> 16], 1);
    __syncthreads();
    int h = 0;
    if (tid < 128) h = hist[tid];
    for (int off = 1; off < 128; off <<= 1) {
        int v = 0;
        if (tid < 128 && tid >= off) v = hist[tid - off];
        __syncthreads();
        if (tid < 128) hist[tid] += v;
        __syncthreads();
    }
    if (tid < 128) {
        int excl = hist[tid] - h;
        cur[tid] = excl;
        int node = node0 + tid;
        if (node < NN) {
            nodeinfo[t * NN + node] = (u32)(b * CAP + excl) | ((u32)h << 20);
            dinv[t * NN + node] = rsqrtf(1.0f + (float)h);
        }
    }
    __syncthreads();
    u16* sl = srclist + (size_t)t * NB2 * CAP;
    for (int i = tid; i < tot; i += 256) {
        u32 rec = recs[i];
        int d = rec >> 16;
        int p = atomicAdd(&cur[d], 1);
        sl[(size_t)b * CAP + p] = (u16)(rec & 0xFFFF);
    }
}

// ---------------- W transpose + bf16 convert (once per t) ----------------
__global__ __launch_bounds__(256) void wt_prep_kernel(const float* __restrict__ Wg, u16* __restrict__ wt) {
    int t = blockIdx.x;
    const float* w = Wg + t * FF * HH;
    u16* o = wt + (size_t)t * HH * FF;
    for (int i = threadIdx.x; i < FF * HH; i += 256) {
        int k = i >> 6, c = i & 63;
        o[c * FF + k] = cvt_bf16(w[i]);
    }
}

// ---------------- y = (x @ Wg) * dinv via bf16 MFMA + LDS-transposed coalesced epilogue ----------------
// 128 rows/block (2x16-row tiles per wave -> 32 MFMAs, 2x setup amortization). The D-fragment
// is column-sliced per lane (col=l15, rows rbase..+3), so direct row-major stores were 16
// scalar 2B globals/thread (store-issue bound, ~116us). Now: scale + 2B writes into padded
// LDS [128][72], then block-wide coalesced uint4 stores (4 x 16B/thread, 128B-contig rows).
__global__ __launch_bounds__(256) void xw_kernel(const float* __restrict__ x, const u16* __restrict__ wt,
                                                 const float* __restrict__ dinv, u16* __restrict__ y) {
    int t = blockIdx.y;
    int row0 = blockIdx.x * 128;
    int tid = threadIdx.x;
    int w = tid >> 6, lane = tid & 63;
    int l15 = lane & 15, lg = lane >> 4;
    __shared__ __align__(16) u16 ylds[128][72];   // 144B row stride: 16B-aligned, bank-spread
    const float* xt = x + (size_t)t * NN * FF;
    const u16* wtt = wt + (size_t)t * HH * FF;

    f32x4 d[2][4] = {{{0,0,0,0},{0,0,0,0},{0,0,0,0},{0,0,0,0}},
                     {{0,0,0,0},{0,0,0,0},{0,0,0,0},{0,0,0,0}}};
    #pragma unroll
    for (int k0 = 0; k0 < 128; k0 += 32) {
        int kb = k0 + lg * 8;
        union { bf16x8 v; __hip_bfloat162 h[4]; } au[2];
        #pragma unroll
        for (int s = 0; s < 2; ++s) {
            int arow = row0 + w * 32 + s * 16 + l15;
            if (arow < NN) {
                float4 f0 = *reinterpret_cast<const float4*>(&xt[(size_t)arow * FF + kb]);
                float4 f1 = *reinterpret_cast<const float4*>(&xt[(size_t)arow * FF + kb + 4]);
                au[s].h[0] = __float22bfloat162_rn(make_float2(f0.x, f0.y));
                au[s].h[1] = __float22bfloat162_rn(make_float2(f0.z, f0.w));
                au[s].h[2] = __float22bfloat162_rn(make_float2(f1.x, f1.y));
                au[s].h[3] = __float22bfloat162_rn(make_float2(f1.z, f1.w));
            } else {
                au[s].v = (bf16x8){0,0,0,0,0,0,0,0};
            }
        }
        #pragma unroll
        for (int n = 0; n < 4; ++n) {
            bf16x8 bf = *reinterpret_cast<const bf16x8*>(&wtt[(size_t)(n * 16 + l15) * FF + kb]);
            d[0][n] = __builtin_amdgcn_mfma_f32_16x16x32_bf16(au[0].v, bf, d[0][n], 0, 0, 0);
            d[1][n] = __builtin_amdgcn_mfma_f32_16x16x32_bf16(au[1].v, bf, d[1][n], 0, 0, 0);
        }
    }
    // scale by dinv, write column-fragments to LDS (cheap 2B LDS writes)
    #pragma unroll
    for (int s = 0; s < 2; ++s) {
        int rl = w * 32 + s * 16 + lg * 4;       // local row base of this lane's fragment
        float dv[4];
        #pragma unroll
        for (int i = 0; i < 4; ++i) {
            int grow = row0 + rl + i;
            dv[i] = (grow < NN) ? dinv[t * NN + grow] : 0.f;
        }
        #pragma unroll
        for (int n = 0; n < 4; ++n) {
            int col = n * 16 + l15;
            #pragma unroll
            for (int i = 0; i < 4; ++i)
                ylds[rl + i][col] = cvt_bf16(d[s][n][i] * dv[i]);
        }
    }
    __syncthreads();
    // coalesced dump: 128 rows x 128B = 1024 uint4; 4 per thread
    u16* yt = y + (size_t)t * NN * HH;
    #pragma unroll
    for (int it = 0; it < 4; ++it) {
        int idx = it * 256 + tid;
        int r = idx >> 3, c8 = (idx & 7) * 8;
        int grow = row0 + r;
        if (grow < NN)
            *reinterpret_cast<uint4*>(&yt[(size_t)grow * HH + c8]) =
                *reinterpret_cast<const uint4*>(&ylds[r][c8]);
    }
}

// ---------------- gather-aggregate over all T (single pass, full 128B rows) ----------------
// EXACT r8 structure (best measured: 177us @ 401MB compulsory floor, 2.39TB/s).
__global__ __launch_bounds__(256) void agg_kernel(const u16* __restrict__ y, const float* __restrict__ dinv,
                                                  const u32* __restrict__ nodeinfo, const u16* __restrict__ srclist,
                                                  const float* __restrict__ bg, float* __restrict__ acc) {
    int node = blockIdx.x * 4 + (threadIdx.x >> 6);
    int lane = threadIdx.x & 63;
    int sub = lane >> 4;            // edge slot 0..3
    int fo = lane & 15;             // feature quad: feats fo*4 .. fo*4+3
    float a0 = 0.f, a1 = 0.f, a2 = 0.f, a3 = 0.f;
    for (int t = 0; t < TT; ++t) {
        const u16* yt = y + (size_t)t * NN * HH;
        u32 info = nodeinfo[t * NN + node];
        int cnt = info >> 20;
        const u16* sl = srclist + (size_t)t * NB2 * CAP + (info & 0xFFFFF);
        float s0 = 0.f, s1 = 0.f, s2 = 0.f, s3 = 0.f;
        int j = 0;
        for (; j + 16 <= cnt; j += 16) {
            int e0 = sl[j + sub], e1 = sl[j + 4 + sub], e2 = sl[j + 8 + sub], e3 = sl[j + 12 + sub];
            uint2 v0 = *reinterpret_cast<const uint2*>(&yt[(size_t)e0 * HH + fo * 4]);
            uint2 v1 = *reinterpret_cast<const uint2*>(&yt[(size_t)e1 * HH + fo * 4]);
            uint2 v2 = *reinterpret_cast<const uint2*>(&yt[(size_t)e2 * HH + fo * 4]);
            uint2 v3 = *reinterpret_cast<const uint2*>(&yt[(size_t)e3 * HH + fo * 4]);
            s0 += (bflo(v0.x) + bflo(v1.x)) + (bflo(v2.x) + bflo(v3.x));
            s1 += (bfhi(v0.x) + bfhi(v1.x)) + (bfhi(v2.x) + bfhi(v3.x));
            s2 += (bflo(v0.y) + bflo(v1.y)) + (bflo(v2.y) + bflo(v3.y));
            s3 += (bfhi(v0.y) + bfhi(v1.y)) + (bfhi(v2.y) + bfhi(v3.y));
        }
        for (; j < cnt; j += 4) {
            int e = j + sub;
            uint2 v = make_uint2(0u, 0u);
            if (e < cnt) {
                int srcid = sl[e];
                v = *reinterpret_cast<const uint2*>(&yt[(size_t)srcid * HH + fo * 4]);
            }
            s0 += bflo(v.x);
            s1 += bfhi(v.x);
            s2 += bflo(v.y);
            s3 += bfhi(v.y);
        }
        s0 += __shfl_xor(s0, 16, 64); s0 += __shfl_xor(s0, 32, 64);
        s1 += __shfl_xor(s1, 16, 64); s1 += __shfl_xor(s1, 32, 64);
        s2 += __shfl_xor(s2, 16, 64); s2 += __shfl_xor(s2, 32, 64);
        s3 += __shfl_xor(s3, 16, 64); s3 += __shfl_xor(s3, 32, 64);
        // self loop (y already scaled by src dinv)
        uint2 sv = *reinterpret_cast<const uint2*>(&yt[(size_t)node * HH + fo * 4]);
        s0 += bflo(sv.x);
        s1 += bfhi(sv.x);
        s2 += bflo(sv.y);
        s3 += bfhi(sv.y);
        float dvv = dinv[t * NN + node];
        float4 bgv = *reinterpret_cast<const float4*>(&bg[t * HH + fo * 4]);
        a0 += fmaxf(dvv * s0 + bgv.x, 0.f);
        a1 += fmaxf(dvv * s1 + bgv.y, 0.f);
        a2 += fmaxf(dvv * s2 + bgv.z, 0.f);
        a3 += fmaxf(dvv * s3 + bgv.w, 0.f);
    }
    if (sub == 0) {
        float4 o = make_float4(a0, a1, a2, a3);
        *reinterpret_cast<float4*>(&acc[(size_t)node * HH + fo * 4]) = o;
    }
}

// ---------------- per-node MLP head + log_softmax ----------------
__global__ __launch_bounds__(256) void head_kernel(const float* __restrict__ acc,
                                                   const float* __restrict__ W1, const float* __restrict__ b1,
                                                   const float* __restrict__ W2, const float* __restrict__ b2,
                                                   const float* __restrict__ W3, const float* __restrict__ b3,
                                                   float* __restrict__ out) {
    __shared__ float w1[64 * 32], w2[32 * 16], w3[16 * 4], bb1[32], bb2[16], bb3[4];
    int tid = threadIdx.x;
    for (int i = tid; i < 2048; i += 256) w1[i] = W1[i];
    for (int i = tid; i < 512; i += 256) w2[i] = W2[i];
    if (tid < 64) w3[tid] = W3[tid];
    if (tid < 32) bb1[tid] = b1[tid];
    if (tid < 16) bb2[tid] = b2[tid];
    if (tid < 4) bb3[tid] = b3[tid];
    __syncthreads();
    int node = blockIdx.x * 256 + tid;
    if (node >= NN) return;

    float a[64];
    #pragma unroll
    for (int k = 0; k < 64; ++k) a[k] = acc[(size_t)node * HH + k];

    float h1[32];
    for (int j = 0; j < 32; ++j) {
        float s = bb1[j];
        #pragma unroll
        for (int k = 0; k < 64; ++k) s += a[k] * w1[k * 32 + j];
        h1[j] = fmaxf(s, 0.f);
    }
    float h2[16];
    for (int j = 0; j < 16; ++j) {
        float s = bb2[j];
        #pragma unroll
        for (int k = 0; k < 32; ++k) s += h1[k] * w2[k * 16 + j];
        h2[j] = fmaxf(s, 0.f);
    }
    float l[4];
    for (int c = 0; c < 4; ++c) {
        float s = bb3[c];
        #pragma unroll
        for (int k = 0; k < 16; ++k) s += h2[k] * w3[k * 4 + c];
        l[c] = s;
    }
    float m = fmaxf(fmaxf(l[0], l[1]), fmaxf(l[2], l[3]));
    float sum = 0.f;
    #pragma unroll
    for (int c = 0; c < 4; ++c) sum += expf(l[c] - m);
    float lse = logf(sum);
    float4 o;
    o.x = l[0] - m - lse; o.y = l[1] - m - lse; o.z = l[2] - m - lse; o.w = l[3] - m - lse;
    *reinterpret_cast<float4*>(&out[(size_t)node * CC]) = o;
}

extern "C" void kernel_launch(void* const* d_in, const int* in_sizes, int n_in,
                              void* d_out, int out_size, void* d_ws, size_t ws_size,
                              hipStream_t stream) {
    const float* x    = (const float*)d_in[0];
    const int*  edges = (const int*)d_in[1];
    const float* Wg   = (const float*)d_in[2];
    const float* bg   = (const float*)d_in[3];
    const float* W1   = (const float*)d_in[4];
    const float* b1   = (const float*)d_in[5];
    const float* W2   = (const float*)d_in[6];
    const float* b2   = (const float*)d_in[7];
    const float* W3   = (const float*)d_in[8];
    const float* b3   = (const float*)d_in[9];
    float* out = (float*)d_out;

    char* ws = (char*)d_ws;
    size_t o = 0;
    int* gcur      = (int*)(ws + o); o += (size_t)TT * NB2 * 4;            // 12.5 KB
    o = (o + 255) & ~(size_t)255;
    float* dinv    = (float*)(ws + o); o += (size_t)TT * NN * 4;           // 1.6 MB
    u32* nodeinfo  = (u32*)(ws + o); o += (size_t)TT * NN * 4;             // 1.6 MB
    o = (o + 255) & ~(size_t)255;
    u16* wt        = (u16*)(ws + o); o += (size_t)TT * HH * FF * 2;        // 128 KB
    o = (o + 255) & ~(size_t)255;
    u32* binned    = (u32*)(ws + o); o += (size_t)TT * NB2 * CAP * 4;      // 32.0 MB
    u16* srclist   = (u16*)(ws + o); o += (size_t)TT * NB2 * CAP * 2;      // 16.0 MB
    u16* y         = (u16*)(ws + o); o += (size_t)TT * NN * HH * 2;        // 51.2 MB
    float* acc     = (float*)(ws + o); o += (size_t)NN * HH * 4;           // 12.8 MB
    // total ~115 MB

    hipMemsetAsync(gcur, 0, (size_t)TT * NB2 * 4, stream);

    multisplit_kernel<<<BPT * TT, 256, 0, stream>>>(edges, gcur, binned);

    dim3 gsc(NB2, TT);
    csr_scatter_kernel<<<gsc, 256, 0, stream>>>(binned, gcur, srclist, nodeinfo, dinv);

    wt_prep_kernel<<<TT, 256, 0, stream>>>(Wg, wt);

    dim3 gx(NB2, TT);
    xw_kernel<<<gx, 256, 0, stream>>>(x, wt, dinv, y);

    agg_kernel<<<12500, 256, 0, stream>>>(y, dinv, nodeinfo, srclist, bg, acc);

    head_kernel<<<196, 256, 0, stream>>>(acc, W1, b1, W2, b2, W3, b3, out);
}

// Round 14
// 362.557 us; speedup vs baseline: 1.0784x; 1.0119x over previous
//
#include <hip/hip_runtime.h>
#include <hip/hip_bf16.h>

#define TT 8
#define NN 50000
#define FF 128
#define HH 64
#define CC 4
#define EE 800000
#define NB2 391           // buckets of 128 nodes (ceil(50000/128))
#define CAP 2560          // padded records per (t,bucket): mean 2048, sd ~45 -> 11 sigma
#define BPT 128           // multisplit blocks per timestep (was 64: 2 blocks/CU -> 4)

typedef unsigned short u16;
typedef unsigned int u32;
typedef __attribute__((ext_vector_type(8))) short bf16x8;
typedef __attribute__((ext_vector_type(4))) float f32x4;

static __device__ __forceinline__ float bflo(u32 w) {
    union { unsigned int i; float f; } v; v.i = w << 16; return v.f;
}
static __device__ __forceinline__ float bfhi(u32 w) {
    union { unsigned int i; float f; } v; v.i = w & 0xFFFF0000u; return v.f;
}
static __device__ __forceinline__ u16 cvt_bf16(float f) {
    __hip_bfloat16 b = __float2bfloat16(f);          // native RNE
    return *reinterpret_cast<u16*>(&b);
}

// ---------------- multisplit: edges -> 64B-aligned padded bucket windows ----------------
__global__ __launch_bounds__(256) void multisplit_kernel(const int* __restrict__ edges,
                                                         int* __restrict__ gcur, u32* __restrict__ binned) {
    __shared__ u32 sbuf[NB2][16];
    __shared__ int scnt[NB2];
    int bid = blockIdx.x;
    int t = bid & 7;
    int blk = bid >> 3;                       // 0..BPT-1
    const int per = (EE + BPT - 1) / BPT;     // 6250
    int e0 = blk * per;
    int e1 = e0 + per; if (e1 > EE) e1 = EE;

    for (int i = threadIdx.x; i < NB2; i += 256) scnt[i] = 0;
    __syncthreads();

    const int* es = edges + (size_t)(t * 2 + 0) * EE;
    const int* ed = edges + (size_t)(t * 2 + 1) * EE;
    int* gc = gcur + t * NB2;
    u32* bb = binned + (size_t)t * NB2 * CAP;

    for (int base = e0; base < e1; base += 512) {
        u32 recA = 0, recB = 0; int bA = -1, bB = -1;
        int eA = base + threadIdx.x;
        int eB = base + 256 + threadIdx.x;
        if (eA < e1) {
            int src = es[eA], dst = ed[eA];
            bA = dst >> 7;
            recA = (u32)src | ((u32)(dst & 127) << 16);
            int p = atomicAdd(&scnt[bA], 1);
            if (p < 16) { sbuf[bA][p] = recA; bA = -1; }
        }
        if (eB < e1) {
            int src = es[eB], dst = ed[eB];
            bB = dst >> 7;
            recB = (u32)src | ((u32)(dst & 127) << 16);
            int p = atomicAdd(&scnt[bB], 1);
            if (p < 16) { sbuf[bB][p] = recB; bB = -1; }
        }
        __syncthreads();
        // flush any full 64B line
        for (int fb = threadIdx.x; fb < NB2; fb += 256) {
            if (scnt[fb] >= 16) {
                int g = atomicAdd(&gc[fb], 16);
                uint4* dp = (uint4*)(bb + (size_t)fb * CAP + g);
                uint4* sp = (uint4*)&sbuf[fb][0];
                dp[0] = sp[0]; dp[1] = sp[1]; dp[2] = sp[2]; dp[3] = sp[3];
                scnt[fb] = 0;                            // pendings re-append below
            }
        }
        __syncthreads();
        if (bA >= 0) {                                   // pending retry (count was >16)
            int p = atomicAdd(&scnt[bA], 1);
            if (p < 16) sbuf[bA][p] = recA;
            else { int g = atomicAdd(&gc[bA], 1); bb[(size_t)bA * CAP + g] = recA; }  // ultra-rare
        }
        if (bB >= 0) {
            int p = atomicAdd(&scnt[bB], 1);
            if (p < 16) sbuf[bB][p] = recB;
            else { int g = atomicAdd(&gc[bB], 1); bb[(size_t)bB * CAP + g] = recB; }
        }
        __syncthreads();
    }
    // residual (<16 per bucket) partial flush
    for (int fb = threadIdx.x; fb < NB2; fb += 256) {
        int c = scnt[fb];
        if (c > 0) {
            int g = atomicAdd(&gc[fb], c);
            for (int k = 0; k < c; ++k) bb[(size_t)fb * CAP + g + k] = sbuf[fb][k];
        }
    }
}

// ---------------- per-bucket: local degree hist + wave-scan -> CSR scatter + nodeinfo + dinv ----------------
__global__ __launch_bounds__(256) void csr_scatter_kernel(const u32* __restrict__ binned, const int* __restrict__ gcur,
                                                          u16* __restrict__ srclist, u32* __restrict__ nodeinfo,
                                                          float* __restrict__ dinv) {
    __shared__ u32 recs[CAP];
    __shared__ int hist[128];
    __shared__ int cur[128];
    int b = blockIdx.x, t = blockIdx.y, tid = threadIdx.x;
    int node0 = b * 128;
    int tot = gcur[t * NB2 + b];
    const u32* win = binned + ((size_t)t * NB2 + b) * CAP;

    for (int i = tid; i < tot; i += 256) recs[i] = win[i];
    if (tid < 128) hist[tid] = 0;
    __syncthreads();
    for (int i = tid; i < tot; i += 256) atomicAdd(&hist[recs[i] >> 16], 1);
    __syncthreads();
    // wave 0 scans 128 counters (2/lane, shfl_up over 64 lanes) -> 1 barrier instead of 14
    if (tid < 64) {
        int v0 = hist[2 * tid], v1 = hist[2 * tid + 1];
        int pair = v0 + v1;
        int inc = pair;
        #pragma unroll
        for (int off = 1; off < 64; off <<= 1) {
            int u = __shfl_up(inc, off, 64);
            if (tid >= off) inc += u;
        }
        int exclp = inc - pair;
        cur[2 * tid] = exclp;
        cur[2 * tid + 1] = exclp + v0;
        int node = node0 + 2 * tid;
        if (node < NN) {
            nodeinfo[t * NN + node] = (u32)(b * CAP + exclp) | ((u32)v0 << 20);
            dinv[t * NN + node] = rsqrtf(1.0f + (float)v0);
        }
        if (node + 1 < NN) {
            nodeinfo[t * NN + node + 1] = (u32)(b * CAP + exclp + v0) | ((u32)v1 << 20);
            dinv[t * NN + node + 1] = rsqrtf(1.0f + (float)v1);
        }
    }
    __syncthreads();
    u16* sl = srclist + (size_t)t * NB2 * CAP;
    for (int i = tid; i < tot; i += 256) {
        u32 rec = recs[i];
        int d = rec >> 16;
        int p = atomicAdd(&cur[d], 1);
        sl[(size_t)b * CAP + p] = (u16)(rec & 0xFFFF);
    }
}

// ---------------- W transpose + bf16 convert (once per t) ----------------
__global__ __launch_bounds__(256) void wt_prep_kernel(const float* __restrict__ Wg, u16* __restrict__ wt) {
    int t = blockIdx.x;
    const float* w = Wg + t * FF * HH;
    u16* o = wt + (size_t)t * HH * FF;
    for (int i = threadIdx.x; i < FF * HH; i += 256) {
        int k = i >> 6, c = i & 63;
        o[c * FF + k] = cvt_bf16(w[i]);
    }
}

// ---------------- y = (x @ Wg) * dinv via bf16 MFMA + LDS-transposed coalesced epilogue ----------------
// 512 threads, 256 rows/block (8 waves x 2x16-row tiles): 2x setup amortization vs r13.
__global__ __launch_bounds__(512) void xw_kernel(const float* __restrict__ x, const u16* __restrict__ wt,
                                                 const float* __restrict__ dinv, u16* __restrict__ y) {
    int t = blockIdx.y;
    int row0 = blockIdx.x * 256;
    int tid = threadIdx.x;
    int w = tid >> 6, lane = tid & 63;
    int l15 = lane & 15, lg = lane >> 4;
    __shared__ __align__(16) u16 ylds[256][72];   // 144B row stride: 16B-aligned, bank-spread
    const float* xt = x + (size_t)t * NN * FF;
    const u16* wtt = wt + (size_t)t * HH * FF;

    f32x4 d[2][4] = {{{0,0,0,0},{0,0,0,0},{0,0,0,0},{0,0,0,0}},
                     {{0,0,0,0},{0,0,0,0},{0,0,0,0},{0,0,0,0}}};
    #pragma unroll
    for (int k0 = 0; k0 < 128; k0 += 32) {
        int kb = k0 + lg * 8;
        union { bf16x8 v; __hip_bfloat162 h[4]; } au[2];
        #pragma unroll
        for (int s = 0; s < 2; ++s) {
            int arow = row0 + w * 32 + s * 16 + l15;
            if (arow < NN) {
                float4 f0 = *reinterpret_cast<const float4*>(&xt[(size_t)arow * FF + kb]);
                float4 f1 = *reinterpret_cast<const float4*>(&xt[(size_t)arow * FF + kb + 4]);
                au[s].h[0] = __float22bfloat162_rn(make_float2(f0.x, f0.y));
                au[s].h[1] = __float22bfloat162_rn(make_float2(f0.z, f0.w));
                au[s].h[2] = __float22bfloat162_rn(make_float2(f1.x, f1.y));
                au[s].h[3] = __float22bfloat162_rn(make_float2(f1.z, f1.w));
            } else {
                au[s].v = (bf16x8){0,0,0,0,0,0,0,0};
            }
        }
        #pragma unroll
        for (int n = 0; n < 4; ++n) {
            bf16x8 bf = *reinterpret_cast<const bf16x8*>(&wtt[(size_t)(n * 16 + l15) * FF + kb]);
            d[0][n] = __builtin_amdgcn_mfma_f32_16x16x32_bf16(au[0].v, bf, d[0][n], 0, 0, 0);
            d[1][n] = __builtin_amdgcn_mfma_f32_16x16x32_bf16(au[1].v, bf, d[1][n], 0, 0, 0);
        }
    }
    // scale by dinv, write column-fragments to LDS (cheap 2B LDS writes)
    #pragma unroll
    for (int s = 0; s < 2; ++s) {
        int rl = w * 32 + s * 16 + lg * 4;       // local row base of this lane's fragment
        float dv[4];
        #pragma unroll
        for (int i = 0; i < 4; ++i) {
            int grow = row0 + rl + i;
            dv[i] = (grow < NN) ? dinv[t * NN + grow] : 0.f;
        }
        #pragma unroll
        for (int n = 0; n < 4; ++n) {
            int col = n * 16 + l15;
            #pragma unroll
            for (int i = 0; i < 4; ++i)
                ylds[rl + i][col] = cvt_bf16(d[s][n][i] * dv[i]);
        }
    }
    __syncthreads();
    // coalesced dump: 256 rows x 128B = 2048 uint4; 4 per thread
    u16* yt = y + (size_t)t * NN * HH;
    #pragma unroll
    for (int it = 0; it < 4; ++it) {
        int idx = it * 512 + tid;
        int r = idx >> 3, c8 = (idx & 7) * 8;
        int grow = row0 + r;
        if (grow < NN)
            *reinterpret_cast<uint4*>(&yt[(size_t)grow * HH + c8]) =
                *reinterpret_cast<const uint4*>(&ylds[r][c8]);
    }
}

// ---------------- gather-aggregate (r8 structure), t-range pass; pass 2 accumulates ----------------
// Split into [0,4) and [4,8) so each half (~90us) leaves top-5 slots for other kernels
// (diagnostic: if xw > agg-half it must appear). Sums are sub-uniform after shfl, so
// initializing a0..a3 from acc on all lanes is exact.
__global__ __launch_bounds__(256) void agg_kernel(const u16* __restrict__ y, const float* __restrict__ dinv,
                                                  const u32* __restrict__ nodeinfo, const u16* __restrict__ srclist,
                                                  const float* __restrict__ bg, float* __restrict__ acc,
                                                  int t0, int t1, int first) {
    int node = blockIdx.x * 4 + (threadIdx.x >> 6);
    int lane = threadIdx.x & 63;
    int sub = lane >> 4;            // edge slot 0..3
    int fo = lane & 15;             // feature quad: feats fo*4 .. fo*4+3
    float a0, a1, a2, a3;
    if (first) {
        a0 = a1 = a2 = a3 = 0.f;
    } else {
        float4 pv = *reinterpret_cast<const float4*>(&acc[(size_t)node * HH + fo * 4]);
        a0 = pv.x; a1 = pv.y; a2 = pv.z; a3 = pv.w;
    }
    for (int t = t0; t < t1; ++t) {
        const u16* yt = y + (size_t)t * NN * HH;
        u32 info = nodeinfo[t * NN + node];
        int cnt = info >> 20;
        const u16* sl = srclist + (size_t)t * NB2 * CAP + (info & 0xFFFFF);
        float s0 = 0.f, s1 = 0.f, s2 = 0.f, s3 = 0.f;
        int j = 0;
        for (; j + 16 <= cnt; j += 16) {
            int e0 = sl[j + sub], e1 = sl[j + 4 + sub], e2 = sl[j + 8 + sub], e3 = sl[j + 12 + sub];
            uint2 v0 = *reinterpret_cast<const uint2*>(&yt[(size_t)e0 * HH + fo * 4]);
            uint2 v1 = *reinterpret_cast<const uint2*>(&yt[(size_t)e1 * HH + fo * 4]);
            uint2 v2 = *reinterpret_cast<const uint2*>(&yt[(size_t)e2 * HH + fo * 4]);
            uint2 v3 = *reinterpret_cast<const uint2*>(&yt[(size_t)e3 * HH + fo * 4]);
            s0 += (bflo(v0.x) + bflo(v1.x)) + (bflo(v2.x) + bflo(v3.x));
            s1 += (bfhi(v0.x) + bfhi(v1.x)) + (bfhi(v2.x) + bfhi(v3.x));
            s2 += (bflo(v0.y) + bflo(v1.y)) + (bflo(v2.y) + bflo(v3.y));
            s3 += (bfhi(v0.y) + bfhi(v1.y)) + (bfhi(v2.y) + bfhi(v3.y));
        }
        for (; j < cnt; j += 4) {
            int e = j + sub;
            uint2 v = make_uint2(0u, 0u);
            if (e < cnt) {
                int srcid = sl[e];
                v = *reinterpret_cast<const uint2*>(&yt[(size_t)srcid * HH + fo * 4]);
            }
            s0 += bflo(v.x);
            s1 += bfhi(v.x);
            s2 += bflo(v.y);
            s3 += bfhi(v.y);
        }
        s0 += __shfl_xor(s0, 16, 64); s0 += __shfl_xor(s0, 32, 64);
        s1 += __shfl_xor(s1, 16, 64); s1 += __shfl_xor(s1, 32, 64);
        s2 += __shfl_xor(s2, 16, 64); s2 += __shfl_xor(s2, 32, 64);
        s3 += __shfl_xor(s3, 16, 64); s3 += __shfl_xor(s3, 32, 64);
        // self loop (y already scaled by src dinv)
        uint2 sv = *reinterpret_cast<const uint2*>(&yt[(size_t)node * HH + fo * 4]);
        s0 += bflo(sv.x);
        s1 += bfhi(sv.x);
        s2 += bflo(sv.y);
        s3 += bfhi(sv.y);
        float dvv = dinv[t * NN + node];
        float4 bgv = *reinterpret_cast<const float4*>(&bg[t * HH + fo * 4]);
        a0 += fmaxf(dvv * s0 + bgv.x, 0.f);
        a1 += fmaxf(dvv * s1 + bgv.y, 0.f);
        a2 += fmaxf(dvv * s2 + bgv.z, 0.f);
        a3 += fmaxf(dvv * s3 + bgv.w, 0.f);
    }
    if (sub == 0) {
        float4 o = make_float4(a0, a1, a2, a3);
        *reinterpret_cast<float4*>(&acc[(size_t)node * HH + fo * 4]) = o;
    }
}

// ---------------- per-node MLP head + log_softmax ----------------
__global__ __launch_bounds__(256) void head_kernel(const float* __restrict__ acc,
                                                   const float* __restrict__ W1, const float* __restrict__ b1,
                                                   const float* __restrict__ W2, const float* __restrict__ b2,
                                                   const float* __restrict__ W3, const float* __restrict__ b3,
                                                   float* __restrict__ out) {
    __shared__ float w1[64 * 32], w2[32 * 16], w3[16 * 4], bb1[32], bb2[16], bb3[4];
    int tid = threadIdx.x;
    for (int i = tid; i < 2048; i += 256) w1[i] = W1[i];
    for (int i = tid; i < 512; i += 256) w2[i] = W2[i];
    if (tid < 64) w3[tid] = W3[tid];
    if (tid < 32) bb1[tid] = b1[tid];
    if (tid < 16) bb2[tid] = b2[tid];
    if (tid < 4) bb3[tid] = b3[tid];
    __syncthreads();
    int node = blockIdx.x * 256 + tid;
    if (node >= NN) return;

    float a[64];
    #pragma unroll
    for (int k = 0; k < 64; ++k) a[k] = acc[(size_t)node * HH + k];

    float h1[32];
    for (int j = 0; j < 32; ++j) {
        float s = bb1[j];
        #pragma unroll
        for (int k = 0; k < 64; ++k) s += a[k] * w1[k * 32 + j];
        h1[j] = fmaxf(s, 0.f);
    }
    float h2[16];
    for (int j = 0; j < 16; ++j) {
        float s = bb2[j];
        #pragma unroll
        for (int k = 0; k < 32; ++k) s += h1[k] * w2[k * 16 + j];
        h2[j] = fmaxf(s, 0.f);
    }
    float l[4];
    for (int c = 0; c < 4; ++c) {
        float s = bb3[c];
        #pragma unroll
        for (int k = 0; k < 16; ++k) s += h2[k] * w3[k * 4 + c];
        l[c] = s;
    }
    float m = fmaxf(fmaxf(l[0], l[1]), fmaxf(l[2], l[3]));
    float sum = 0.f;
    #pragma unroll
    for (int c = 0; c < 4; ++c) sum += expf(l[c] - m);
    float lse = logf(sum);
    float4 o;
    o.x = l[0] - m - lse; o.y = l[1] - m - lse; o.z = l[2] - m - lse; o.w = l[3] - m - lse;
    *reinterpret_cast<float4*>(&out[(size_t)node * CC]) = o;
}

extern "C" void kernel_launch(void* const* d_in, const int* in_sizes, int n_in,
                              void* d_out, int out_size, void* d_ws, size_t ws_size,
                              hipStream_t stream) {
    const float* x    = (const float*)d_in[0];
    const int*  edges = (const int*)d_in[1];
    const float* Wg   = (const float*)d_in[2];
    const float* bg   = (const float*)d_in[3];
    const float* W1   = (const float*)d_in[4];
    const float* b1   = (const float*)d_in[5];
    const float* W2   = (const float*)d_in[6];
    const float* b2   = (const float*)d_in[7];
    const float* W3   = (const float*)d_in[8];
    const float* b3   = (const float*)d_in[9];
    float* out = (float*)d_out;

    char* ws = (char*)d_ws;
    size_t o = 0;
    int* gcur      = (int*)(ws + o); o += (size_t)TT * NB2 * 4;            // 12.5 KB
    o = (o + 255) & ~(size_t)255;
    float* dinv    = (float*)(ws + o); o += (size_t)TT * NN * 4;           // 1.6 MB
    u32* nodeinfo  = (u32*)(ws + o); o += (size_t)TT * NN * 4;             // 1.6 MB
    o = (o + 255) & ~(size_t)255;
    u16* wt        = (u16*)(ws + o); o += (size_t)TT * HH * FF * 2;        // 128 KB
    o = (o + 255) & ~(size_t)255;
    u32* binned    = (u32*)(ws + o); o += (size_t)TT * NB2 * CAP * 4;      // 32.0 MB
    u16* srclist   = (u16*)(ws + o); o += (size_t)TT * NB2 * CAP * 2;      // 16.0 MB
    u16* y         = (u16*)(ws + o); o += (size_t)TT * NN * HH * 2;        // 51.2 MB
    float* acc     = (float*)(ws + o); o += (size_t)NN * HH * 4;           // 12.8 MB
    // total ~115 MB

    hipMemsetAsync(gcur, 0, (size_t)TT * NB2 * 4, stream);

    multisplit_kernel<<<BPT * TT, 256, 0, stream>>>(edges, gcur, binned);

    dim3 gsc(NB2, TT);
    csr_scatter_kernel<<<gsc, 256, 0, stream>>>(binned, gcur, srclist, nodeinfo, dinv);

    wt_prep_kernel<<<TT, 256, 0, stream>>>(Wg, wt);

    dim3 gx(196, TT);
    xw_kernel<<<gx, 512, 0, stream>>>(x, wt, dinv, y);

    agg_kernel<<<12500, 256, 0, stream>>>(y, dinv, nodeinfo, srclist, bg, acc, 0, 4, 1);
    agg_kernel<<<12500, 256, 0, stream>>>(y, dinv, nodeinfo, srclist, bg, acc, 4, 8, 0);

    head_kernel<<<196, 256, 0, stream>>>(acc, W1, b1, W2, b2, W3, b3, out);
}

// Round 15
// 350.594 us; speedup vs baseline: 1.1152x; 1.0341x over previous
//
#include <hip/hip_runtime.h>
#include <hip/hip_bf16.h>

#define TT 8
#define NN 50000
#define FF 128
#define HH 64
#define CC 4
#define EE 800000
#define NB2 391           // buckets of 128 nodes (ceil(50000/128))
#define CAP 2560          // padded records per (t,bucket): mean 2048, sd ~45 -> 11 sigma
#define BPT 128           // multisplit blocks per timestep

typedef unsigned short u16;
typedef unsigned int u32;
typedef __attribute__((ext_vector_type(8))) short bf16x8;
typedef __attribute__((ext_vector_type(4))) float f32x4;

static __device__ __forceinline__ float bflo(u32 w) {
    union { unsigned int i; float f; } v; v.i = w << 16; return v.f;
}
static __device__ __forceinline__ float bfhi(u32 w) {
    union { unsigned int i; float f; } v; v.i = w & 0xFFFF0000u; return v.f;
}
static __device__ __forceinline__ u16 cvt_bf16(float f) {
    __hip_bfloat16 b = __float2bfloat16(f);          // native RNE
    return *reinterpret_cast<u16*>(&b);
}

// ---------------- zero gcur (replaces hipMemsetAsync: the runtime fill-blit cost ~118us
// in the captured graph for a 12.5KB fill -- measured r14 top-5) ----------------
__global__ __launch_bounds__(256) void zero_gcur_kernel(int* __restrict__ gcur) {
    int i = blockIdx.x * 256 + threadIdx.x;
    if (i < TT * NB2) gcur[i] = 0;
}

// ---------------- multisplit: edges -> 64B-aligned padded bucket windows ----------------
__global__ __launch_bounds__(256) void multisplit_kernel(const int* __restrict__ edges,
                                                         int* __restrict__ gcur, u32* __restrict__ binned) {
    __shared__ u32 sbuf[NB2][16];
    __shared__ int scnt[NB2];
    int bid = blockIdx.x;
    int t = bid & 7;
    int blk = bid >> 3;                       // 0..BPT-1
    const int per = (EE + BPT - 1) / BPT;     // 6250
    int e0 = blk * per;
    int e1 = e0 + per; if (e1 > EE) e1 = EE;

    for (int i = threadIdx.x; i < NB2; i += 256) scnt[i] = 0;
    __syncthreads();

    const int* es = edges + (size_t)(t * 2 + 0) * EE;
    const int* ed = edges + (size_t)(t * 2 + 1) * EE;
    int* gc = gcur + t * NB2;
    u32* bb = binned + (size_t)t * NB2 * CAP;

    for (int base = e0; base < e1; base += 512) {
        u32 recA = 0, recB = 0; int bA = -1, bB = -1;
        int eA = base + threadIdx.x;
        int eB = base + 256 + threadIdx.x;
        if (eA < e1) {
            int src = es[eA], dst = ed[eA];
            bA = dst >> 7;
            recA = (u32)src | ((u32)(dst & 127) << 16);
            int p = atomicAdd(&scnt[bA], 1);
            if (p < 16) { sbuf[bA][p] = recA; bA = -1; }
        }
        if (eB < e1) {
            int src = es[eB], dst = ed[eB];
            bB = dst >> 7;
            recB = (u32)src | ((u32)(dst & 127) << 16);
            int p = atomicAdd(&scnt[bB], 1);
            if (p < 16) { sbuf[bB][p] = recB; bB = -1; }
        }
        __syncthreads();
        // flush any full 64B line
        for (int fb = threadIdx.x; fb < NB2; fb += 256) {
            if (scnt[fb] >= 16) {
                int g = atomicAdd(&gc[fb], 16);
                uint4* dp = (uint4*)(bb + (size_t)fb * CAP + g);
                uint4* sp = (uint4*)&sbuf[fb][0];
                dp[0] = sp[0]; dp[1] = sp[1]; dp[2] = sp[2]; dp[3] = sp[3];
                scnt[fb] = 0;                            // pendings re-append below
            }
        }
        __syncthreads();
        if (bA >= 0) {                                   // pending retry (count was >16)
            int p = atomicAdd(&scnt[bA], 1);
            if (p < 16) sbuf[bA][p] = recA;
            else { int g = atomicAdd(&gc[bA], 1); bb[(size_t)bA * CAP + g] = recA; }  // ultra-rare
        }
        if (bB >= 0) {
            int p = atomicAdd(&scnt[bB], 1);
            if (p < 16) sbuf[bB][p] = recB;
            else { int g = atomicAdd(&gc[bB], 1); bb[(size_t)bB * CAP + g] = recB; }
        }
        __syncthreads();
    }
    // residual (<16 per bucket) partial flush
    for (int fb = threadIdx.x; fb < NB2; fb += 256) {
        int c = scnt[fb];
        if (c > 0) {
            int g = atomicAdd(&gc[fb], c);
            for (int k = 0; k < c; ++k) bb[(size_t)fb * CAP + g + k] = sbuf[fb][k];
        }
    }
}

// ---------------- per-bucket: local degree hist + wave-scan -> CSR scatter + nodeinfo + dinv ----------------
__global__ __launch_bounds__(256) void csr_scatter_kernel(const u32* __restrict__ binned, const int* __restrict__ gcur,
                                                          u16* __restrict__ srclist, u32* __restrict__ nodeinfo,
                                                          float* __restrict__ dinv) {
    __shared__ u32 recs[CAP];
    __shared__ int hist[128];
    __shared__ int cur[128];
    int b = blockIdx.x, t = blockIdx.y, tid = threadIdx.x;
    int node0 = b * 128;
    int tot = gcur[t * NB2 + b];
    const u32* win = binned + ((size_t)t * NB2 + b) * CAP;

    for (int i = tid; i < tot; i += 256) recs[i] = win[i];
    if (tid < 128) hist[tid] = 0;
    __syncthreads();
    for (int i = tid; i < tot; i += 256) atomicAdd(&hist[recs[i] >> 16], 1);
    __syncthreads();
    // wave 0 scans 128 counters (2/lane, shfl_up over 64 lanes) -> 1 barrier instead of 14
    if (tid < 64) {
        int v0 = hist[2 * tid], v1 = hist[2 * tid + 1];
        int pair = v0 + v1;
        int inc = pair;
        #pragma unroll
        for (int off = 1; off < 64; off <<= 1) {
            int u = __shfl_up(inc, off, 64);
            if (tid >= off) inc += u;
        }
        int exclp = inc - pair;
        cur[2 * tid] = exclp;
        cur[2 * tid + 1] = exclp + v0;
        int node = node0 + 2 * tid;
        if (node < NN) {
            nodeinfo[t * NN + node] = (u32)(b * CAP + exclp) | ((u32)v0 << 20);
            dinv[t * NN + node] = rsqrtf(1.0f + (float)v0);
        }
        if (node + 1 < NN) {
            nodeinfo[t * NN + node + 1] = (u32)(b * CAP + exclp + v0) | ((u32)v1 << 20);
            dinv[t * NN + node + 1] = rsqrtf(1.0f + (float)v1);
        }
    }
    __syncthreads();
    u16* sl = srclist + (size_t)t * NB2 * CAP;
    for (int i = tid; i < tot; i += 256) {
        u32 rec = recs[i];
        int d = rec >> 16;
        int p = atomicAdd(&cur[d], 1);
        sl[(size_t)b * CAP + p] = (u16)(rec & 0xFFFF);
    }
}

// ---------------- W transpose + bf16 convert (once per t) ----------------
__global__ __launch_bounds__(256) void wt_prep_kernel(const float* __restrict__ Wg, u16* __restrict__ wt) {
    int t = blockIdx.x;
    const float* w = Wg + t * FF * HH;
    u16* o = wt + (size_t)t * HH * FF;
    for (int i = threadIdx.x; i < FF * HH; i += 256) {
        int k = i >> 6, c = i & 63;
        o[c * FF + k] = cvt_bf16(w[i]);
    }
}

// ---------------- y = (x @ Wg) * dinv via bf16 MFMA + LDS-transposed coalesced epilogue ----------------
__global__ __launch_bounds__(512) void xw_kernel(const float* __restrict__ x, const u16* __restrict__ wt,
                                                 const float* __restrict__ dinv, u16* __restrict__ y) {
    int t = blockIdx.y;
    int row0 = blockIdx.x * 256;
    int tid = threadIdx.x;
    int w = tid >> 6, lane = tid & 63;
    int l15 = lane & 15, lg = lane >> 4;
    __shared__ __align__(16) u16 ylds[256][72];   // 144B row stride: 16B-aligned, bank-spread
    const float* xt = x + (size_t)t * NN * FF;
    const u16* wtt = wt + (size_t)t * HH * FF;

    f32x4 d[2][4] = {{{0,0,0,0},{0,0,0,0},{0,0,0,0},{0,0,0,0}},
                     {{0,0,0,0},{0,0,0,0},{0,0,0,0},{0,0,0,0}}};
    #pragma unroll
    for (int k0 = 0; k0 < 128; k0 += 32) {
        int kb = k0 + lg * 8;
        union { bf16x8 v; __hip_bfloat162 h[4]; } au[2];
        #pragma unroll
        for (int s = 0; s < 2; ++s) {
            int arow = row0 + w * 32 + s * 16 + l15;
            if (arow < NN) {
                float4 f0 = *reinterpret_cast<const float4*>(&xt[(size_t)arow * FF + kb]);
                float4 f1 = *reinterpret_cast<const float4*>(&xt[(size_t)arow * FF + kb + 4]);
                au[s].h[0] = __float22bfloat162_rn(make_float2(f0.x, f0.y));
                au[s].h[1] = __float22bfloat162_rn(make_float2(f0.z, f0.w));
                au[s].h[2] = __float22bfloat162_rn(make_float2(f1.x, f1.y));
                au[s].h[3] = __float22bfloat162_rn(make_float2(f1.z, f1.w));
            } else {
                au[s].v = (bf16x8){0,0,0,0,0,0,0,0};
            }
        }
        #pragma unroll
        for (int n = 0; n < 4; ++n) {
            bf16x8 bf = *reinterpret_cast<const bf16x8*>(&wtt[(size_t)(n * 16 + l15) * FF + kb]);
            d[0][n] = __builtin_amdgcn_mfma_f32_16x16x32_bf16(au[0].v, bf, d[0][n], 0, 0, 0);
            d[1][n] = __builtin_amdgcn_mfma_f32_16x16x32_bf16(au[1].v, bf, d[1][n], 0, 0, 0);
        }
    }
    // scale by dinv, write column-fragments to LDS (cheap 2B LDS writes)
    #pragma unroll
    for (int s = 0; s < 2; ++s) {
        int rl = w * 32 + s * 16 + lg * 4;       // local row base of this lane's fragment
        float dv[4];
        #pragma unroll
        for (int i = 0; i < 4; ++i) {
            int grow = row0 + rl + i;
            dv[i] = (grow < NN) ? dinv[t * NN + grow] : 0.f;
        }
        #pragma unroll
        for (int n = 0; n < 4; ++n) {
            int col = n * 16 + l15;
            #pragma unroll
            for (int i = 0; i < 4; ++i)
                ylds[rl + i][col] = cvt_bf16(d[s][n][i] * dv[i]);
        }
    }
    __syncthreads();
    // coalesced dump: 256 rows x 128B = 2048 uint4; 4 per thread
    u16* yt = y + (size_t)t * NN * HH;
    #pragma unroll
    for (int it = 0; it < 4; ++it) {
        int idx = it * 512 + tid;
        int r = idx >> 3, c8 = (idx & 7) * 8;
        int grow = row0 + r;
        if (grow < NN)
            *reinterpret_cast<uint4*>(&yt[(size_t)grow * HH + c8]) =
                *reinterpret_cast<const uint4*>(&ylds[r][c8]);
    }
}

// ---------------- gather-aggregate over all T (single pass, full 128B rows) ----------------
// EXACT r8 structure (best measured: 177us @ 401MB compulsory floor, 2.39TB/s).
__global__ __launch_bounds__(256) void agg_kernel(const u16* __restrict__ y, const float* __restrict__ dinv,
                                                  const u32* __restrict__ nodeinfo, const u16* __restrict__ srclist,
                                                  const float* __restrict__ bg, float* __restrict__ acc) {
    int node = blockIdx.x * 4 + (threadIdx.x >> 6);
    int lane = threadIdx.x & 63;
    int sub = lane >> 4;            // edge slot 0..3
    int fo = lane & 15;             // feature quad: feats fo*4 .. fo*4+3
    float a0 = 0.f, a1 = 0.f, a2 = 0.f, a3 = 0.f;
    for (int t = 0; t < TT; ++t) {
        const u16* yt = y + (size_t)t * NN * HH;
        u32 info = nodeinfo[t * NN + node];
        int cnt = info >> 20;
        const u16* sl = srclist + (size_t)t * NB2 * CAP + (info & 0xFFFFF);
        float s0 = 0.f, s1 = 0.f, s2 = 0.f, s3 = 0.f;
        int j = 0;
        for (; j + 16 <= cnt; j += 16) {
            int e0 = sl[j + sub], e1 = sl[j + 4 + sub], e2 = sl[j + 8 + sub], e3 = sl[j + 12 + sub];
            uint2 v0 = *reinterpret_cast<const uint2*>(&yt[(size_t)e0 * HH + fo * 4]);
            uint2 v1 = *reinterpret_cast<const uint2*>(&yt[(size_t)e1 * HH + fo * 4]);
            uint2 v2 = *reinterpret_cast<const uint2*>(&yt[(size_t)e2 * HH + fo * 4]);
            uint2 v3 = *reinterpret_cast<const uint2*>(&yt[(size_t)e3 * HH + fo * 4]);
            s0 += (bflo(v0.x) + bflo(v1.x)) + (bflo(v2.x) + bflo(v3.x));
            s1 += (bfhi(v0.x) + bfhi(v1.x)) + (bfhi(v2.x) + bfhi(v3.x));
            s2 += (bflo(v0.y) + bflo(v1.y)) + (bflo(v2.y) + bflo(v3.y));
            s3 += (bfhi(v0.y) + bfhi(v1.y)) + (bfhi(v2.y) + bfhi(v3.y));
        }
        for (; j < cnt; j += 4) {
            int e = j + sub;
            uint2 v = make_uint2(0u, 0u);
            if (e < cnt) {
                int srcid = sl[e];
                v = *reinterpret_cast<const uint2*>(&yt[(size_t)srcid * HH + fo * 4]);
            }
            s0 += bflo(v.x);
            s1 += bfhi(v.x);
            s2 += bflo(v.y);
            s3 += bfhi(v.y);
        }
        s0 += __shfl_xor(s0, 16, 64); s0 += __shfl_xor(s0, 32, 64);
        s1 += __shfl_xor(s1, 16, 64); s1 += __shfl_xor(s1, 32, 64);
        s2 += __shfl_xor(s2, 16, 64); s2 += __shfl_xor(s2, 32, 64);
        s3 += __shfl_xor(s3, 16, 64); s3 += __shfl_xor(s3, 32, 64);
        // self loop (y already scaled by src dinv)
        uint2 sv = *reinterpret_cast<const uint2*>(&yt[(size_t)node * HH + fo * 4]);
        s0 += bflo(sv.x);
        s1 += bfhi(sv.x);
        s2 += bflo(sv.y);
        s3 += bfhi(sv.y);
        float dvv = dinv[t * NN + node];
        float4 bgv = *reinterpret_cast<const float4*>(&bg[t * HH + fo * 4]);
        a0 += fmaxf(dvv * s0 + bgv.x, 0.f);
        a1 += fmaxf(dvv * s1 + bgv.y, 0.f);
        a2 += fmaxf(dvv * s2 + bgv.z, 0.f);
        a3 += fmaxf(dvv * s3 + bgv.w, 0.f);
    }
    if (sub == 0) {
        float4 o = make_float4(a0, a1, a2, a3);
        *reinterpret_cast<float4*>(&acc[(size_t)node * HH + fo * 4]) = o;
    }
}

// ---------------- per-node MLP head + log_softmax ----------------
__global__ __launch_bounds__(256) void head_kernel(const float* __restrict__ acc,
                                                   const float* __restrict__ W1, const float* __restrict__ b1,
                                                   const float* __restrict__ W2, const float* __restrict__ b2,
                                                   const float* __restrict__ W3, const float* __restrict__ b3,
                                                   float* __restrict__ out) {
    __shared__ float w1[64 * 32], w2[32 * 16], w3[16 * 4], bb1[32], bb2[16], bb3[4];
    int tid = threadIdx.x;
    for (int i = tid; i < 2048; i += 256) w1[i] = W1[i];
    for (int i = tid; i < 512; i += 256) w2[i] = W2[i];
    if (tid < 64) w3[tid] = W3[tid];
    if (tid < 32) bb1[tid] = b1[tid];
    if (tid < 16) bb2[tid] = b2[tid];
    if (tid < 4) bb3[tid] = b3[tid];
    __syncthreads();
    int node = blockIdx.x * 256 + tid;
    if (node >= NN) return;

    float a[64];
    #pragma unroll
    for (int k = 0; k < 64; ++k) a[k] = acc[(size_t)node * HH + k];

    float h1[32];
    for (int j = 0; j < 32; ++j) {
        float s = bb1[j];
        #pragma unroll
        for (int k = 0; k < 64; ++k) s += a[k] * w1[k * 32 + j];
        h1[j] = fmaxf(s, 0.f);
    }
    float h2[16];
    for (int j = 0; j < 16; ++j) {
        float s = bb2[j];
        #pragma unroll
        for (int k = 0; k < 32; ++k) s += h1[k] * w2[k * 16 + j];
        h2[j] = fmaxf(s, 0.f);
    }
    float l[4];
    for (int c = 0; c < 4; ++c) {
        float s = bb3[c];
        #pragma unroll
        for (int k = 0; k < 16; ++k) s += h2[k] * w3[k * 4 + c];
        l[c] = s;
    }
    float m = fmaxf(fmaxf(l[0], l[1]), fmaxf(l[2], l[3]));
    float sum = 0.f;
    #pragma unroll
    for (int c = 0; c < 4; ++c) sum += expf(l[c] - m);
    float lse = logf(sum);
    float4 o;
    o.x = l[0] - m - lse; o.y = l[1] - m - lse; o.z = l[2] - m - lse; o.w = l[3] - m - lse;
    *reinterpret_cast<float4*>(&out[(size_t)node * CC]) = o;
}

extern "C" void kernel_launch(void* const* d_in, const int* in_sizes, int n_in,
                              void* d_out, int out_size, void* d_ws, size_t ws_size,
                              hipStream_t stream) {
    const float* x    = (const float*)d_in[0];
    const int*  edges = (const int*)d_in[1];
    const float* Wg   = (const float*)d_in[2];
    const float* bg   = (const float*)d_in[3];
    const float* W1   = (const float*)d_in[4];
    const float* b1   = (const float*)d_in[5];
    const float* W2   = (const float*)d_in[6];
    const float* b2   = (const float*)d_in[7];
    const float* W3   = (const float*)d_in[8];
    const float* b3   = (const float*)d_in[9];
    float* out = (float*)d_out;

    char* ws = (char*)d_ws;
    size_t o = 0;
    int* gcur      = (int*)(ws + o); o += (size_t)TT * NB2 * 4;            // 12.5 KB
    o = (o + 255) & ~(size_t)255;
    float* dinv    = (float*)(ws + o); o += (size_t)TT * NN * 4;           // 1.6 MB
    u32* nodeinfo  = (u32*)(ws + o); o += (size_t)TT * NN * 4;             // 1.6 MB
    o = (o + 255) & ~(size_t)255;
    u16* wt        = (u16*)(ws + o); o += (size_t)TT * HH * FF * 2;        // 128 KB
    o = (o + 255) & ~(size_t)255;
    u32* binned    = (u32*)(ws + o); o += (size_t)TT * NB2 * CAP * 4;      // 32.0 MB
    u16* srclist   = (u16*)(ws + o); o += (size_t)TT * NB2 * CAP * 2;      // 16.0 MB
    u16* y         = (u16*)(ws + o); o += (size_t)TT * NN * HH * 2;        // 51.2 MB
    float* acc     = (float*)(ws + o); o += (size_t)NN * HH * 4;           // 12.8 MB
    // total ~115 MB

    zero_gcur_kernel<<<(TT * NB2 + 255) / 256, 256, 0, stream>>>(gcur);

    multisplit_kernel<<<BPT * TT, 256, 0, stream>>>(edges, gcur, binned);

    dim3 gsc(NB2, TT);
    csr_scatter_kernel<<<gsc, 256, 0, stream>>>(binned, gcur, srclist, nodeinfo, dinv);

    wt_prep_kernel<<<TT, 256, 0, stream>>>(Wg, wt);

    dim3 gx(196, TT);
    xw_kernel<<<gx, 512, 0, stream>>>(x, wt, dinv, y);

    agg_kernel<<<12500, 256, 0, stream>>>(y, dinv, nodeinfo, srclist, bg, acc);

    head_kernel<<<196, 256, 0, stream>>>(acc, W1, b1, W2, b2, W3, b3, out);
}

// Round 17
// 338.329 us; speedup vs baseline: 1.1557x; 1.0362x over previous
//
#include <hip/hip_runtime.h>
#include <hip/hip_bf16.h>

#define TT 8
#define NN 50000
#define FF 128
#define HH 64
#define CC 4
#define EE 800000
#define NB2 391           // buckets of 128 nodes (ceil(50000/128))
#define CAP 2560          // padded records per (t,bucket): mean 2048, sd ~45 -> 11 sigma
#define BPT 125           // multisplit blocks per timestep (125*6400 = 800000; int4-aligned windows)

typedef unsigned short u16;
typedef unsigned int u32;
typedef __attribute__((ext_vector_type(8))) short bf16x8;
typedef __attribute__((ext_vector_type(4))) float f32x4;
typedef __attribute__((ext_vector_type(4))) int i32x4;

static __device__ __forceinline__ float bflo(u32 w) {
    union { unsigned int i; float f; } v; v.i = w << 16; return v.f;
}
static __device__ __forceinline__ float bfhi(u32 w) {
    union { unsigned int i; float f; } v; v.i = w & 0xFFFF0000u; return v.f;
}
static __device__ __forceinline__ u16 cvt_bf16(float f) {
    __hip_bfloat16 b = __float2bfloat16(f);          // native RNE
    return *reinterpret_cast<u16*>(&b);
}

// ---------------- zero gcur ----------------
__global__ __launch_bounds__(256) void zero_gcur_kernel(int* __restrict__ gcur) {
    int i = blockIdx.x * 256 + threadIdx.x;
    if (i < TT * NB2) gcur[i] = 0;
}

// ---------------- multisplit: edges -> 64B-aligned padded bucket windows ----------------
// int4 edge loads (4 edges/thread/round, 1024/round): 1/4 the load instructions and half
// the barrier/flush rounds of the 512-edge scalar version. Only full aligned 64B lines
// are flushed to global.
__global__ __launch_bounds__(256) void multisplit_kernel(const int* __restrict__ edges,
                                                         int* __restrict__ gcur, u32* __restrict__ binned) {
    __shared__ u32 sbuf[NB2][16];
    __shared__ int scnt[NB2];
    int bid = blockIdx.x;
    int t = bid & 7;
    int blk = bid >> 3;                       // 0..BPT-1
    const int per = EE / BPT;                 // 6400 (16B-aligned window start)
    int e0 = blk * per;
    int e1 = e0 + per;

    for (int i = threadIdx.x; i < NB2; i += 256) scnt[i] = 0;
    __syncthreads();

    const int* es = edges + (size_t)(t * 2 + 0) * EE;
    const int* ed = edges + (size_t)(t * 2 + 1) * EE;
    int* gc = gcur + t * NB2;
    u32* bb = binned + (size_t)t * NB2 * CAP;

    for (int base = e0; base < e1; base += 1024) {
        u32 rec[4]; int pb[4];
        int e = base + threadIdx.x * 4;
        int nv = 0;
        if (e + 3 < e1) nv = 4;
        else if (e < e1) nv = e1 - e;
        if (nv == 4) {
            i32x4 s4 = *reinterpret_cast<const i32x4*>(&es[e]);
            i32x4 d4 = *reinterpret_cast<const i32x4*>(&ed[e]);
            #pragma unroll
            for (int q = 0; q < 4; ++q) {
                int b = d4[q] >> 7;
                u32 r = (u32)s4[q] | ((u32)(d4[q] & 127) << 16);
                int p = atomicAdd(&scnt[b], 1);
                if (p < 16) { sbuf[b][p] = r; pb[q] = -1; }
                else { rec[q] = r; pb[q] = b; }
            }
        } else {
            #pragma unroll
            for (int q = 0; q < 4; ++q) {
                pb[q] = -1;
                if (q < nv) {
                    int src = es[e + q], dst = ed[e + q];
                    int b = dst >> 7;
                    u32 r = (u32)src | ((u32)(dst & 127) << 16);
                    int p = atomicAdd(&scnt[b], 1);
                    if (p < 16) sbuf[b][p] = r;
                    else { rec[q] = r; pb[q] = b; }
                }
            }
        }
        __syncthreads();
        // flush any full 64B line
        for (int fb = threadIdx.x; fb < NB2; fb += 256) {
            if (scnt[fb] >= 16) {
                int g = atomicAdd(&gc[fb], 16);
                uint4* dp = (uint4*)(bb + (size_t)fb * CAP + g);
                uint4* sp = (uint4*)&sbuf[fb][0];
                dp[0] = sp[0]; dp[1] = sp[1]; dp[2] = sp[2]; dp[3] = sp[3];
                scnt[fb] = 0;                            // pendings re-append below
            }
        }
        __syncthreads();
        #pragma unroll
        for (int q = 0; q < 4; ++q) {
            if (pb[q] >= 0) {                            // pending retry (count was >16)
                int p = atomicAdd(&scnt[pb[q]], 1);
                if (p < 16) sbuf[pb[q]][p] = rec[q];
                else { int g = atomicAdd(&gc[pb[q]], 1); bb[(size_t)pb[q] * CAP + g] = rec[q]; }  // rare
            }
        }
        __syncthreads();
    }
    // residual (<16 per bucket) partial flush
    for (int fb = threadIdx.x; fb < NB2; fb += 256) {
        int c = scnt[fb];
        if (c > 0) {
            int g = atomicAdd(&gc[fb], c);
            for (int k = 0; k < c; ++k) bb[(size_t)fb * CAP + g + k] = sbuf[fb][k];
        }
    }
}

// ---------------- per-bucket: local degree hist + wave-scan -> CSR scatter + nodeinfo + dinv ----------------
// 512 threads: halves the per-block serial stage/scatter chains vs 256.
__global__ __launch_bounds__(512) void csr_scatter_kernel(const u32* __restrict__ binned, const int* __restrict__ gcur,
                                                          u16* __restrict__ srclist, u32* __restrict__ nodeinfo,
                                                          float* __restrict__ dinv) {
    __shared__ u32 recs[CAP];
    __shared__ int hist[128];
    __shared__ int cur[128];
    int b = blockIdx.x, t = blockIdx.y, tid = threadIdx.x;
    int node0 = b * 128;
    int tot = gcur[t * NB2 + b];
    const u32* win = binned + ((size_t)t * NB2 + b) * CAP;

    for (int i = tid; i < tot; i += 512) recs[i] = win[i];
    if (tid < 128) hist[tid] = 0;
    __syncthreads();
    for (int i = tid; i < tot; i += 512) atomicAdd(&hist[recs[i] >> 16], 1);
    __syncthreads();
    // wave 0 scans 128 counters (2/lane, shfl_up over 64 lanes)
    if (tid < 64) {
        int v0 = hist[2 * tid], v1 = hist[2 * tid + 1];
        int pair = v0 + v1;
        int inc = pair;
        #pragma unroll
        for (int off = 1; off < 64; off <<= 1) {
            int u = __shfl_up(inc, off, 64);
            if (tid >= off) inc += u;
        }
        int exclp = inc - pair;
        cur[2 * tid] = exclp;
        cur[2 * tid + 1] = exclp + v0;
        int node = node0 + 2 * tid;
        if (node < NN) {
            nodeinfo[t * NN + node] = (u32)(b * CAP + exclp) | ((u32)v0 << 20);
            dinv[t * NN + node] = rsqrtf(1.0f + (float)v0);
        }
        if (node + 1 < NN) {
            nodeinfo[t * NN + node + 1] = (u32)(b * CAP + exclp + v0) | ((u32)v1 << 20);
            dinv[t * NN + node + 1] = rsqrtf(1.0f + (float)v1);
        }
    }
    __syncthreads();
    u16* sl = srclist + (size_t)t * NB2 * CAP;
    for (int i = tid; i < tot; i += 512) {
        u32 rec = recs[i];
        int d = rec >> 16;
        int p = atomicAdd(&cur[d], 1);
        sl[(size_t)b * CAP + p] = (u16)(rec & 0xFFFF);
    }
}

// ---------------- W transpose + bf16 convert (once per t) ----------------
__global__ __launch_bounds__(256) void wt_prep_kernel(const float* __restrict__ Wg, u16* __restrict__ wt) {
    int t = blockIdx.x;
    const float* w = Wg + t * FF * HH;
    u16* o = wt + (size_t)t * HH * FF;
    for (int i = threadIdx.x; i < FF * HH; i += 256) {
        int k = i >> 6, c = i & 63;
        o[c * FF + k] = cvt_bf16(w[i]);
    }
}

// ---------------- y = (x @ Wg) * dinv via bf16 MFMA + LDS-transposed coalesced epilogue ----------------
// Nontemporal x loads (ext_vector f32x4: builtin requires vector-of-scalar type, not
// HIP_vector_type struct): x is single-touch; keep L2 capacity for y (agg re-reads it).
__global__ __launch_bounds__(512) void xw_kernel(const float* __restrict__ x, const u16* __restrict__ wt,
                                                 const float* __restrict__ dinv, u16* __restrict__ y) {
    int t = blockIdx.y;
    int row0 = blockIdx.x * 256;
    int tid = threadIdx.x;
    int w = tid >> 6, lane = tid & 63;
    int l15 = lane & 15, lg = lane >> 4;
    __shared__ __align__(16) u16 ylds[256][72];   // 144B row stride: 16B-aligned, bank-spread
    const float* xt = x + (size_t)t * NN * FF;
    const u16* wtt = wt + (size_t)t * HH * FF;

    f32x4 d[2][4] = {{{0,0,0,0},{0,0,0,0},{0,0,0,0},{0,0,0,0}},
                     {{0,0,0,0},{0,0,0,0},{0,0,0,0},{0,0,0,0}}};
    #pragma unroll
    for (int k0 = 0; k0 < 128; k0 += 32) {
        int kb = k0 + lg * 8;
        union { bf16x8 v; __hip_bfloat162 h[4]; } au[2];
        #pragma unroll
        for (int s = 0; s < 2; ++s) {
            int arow = row0 + w * 32 + s * 16 + l15;
            if (arow < NN) {
                f32x4 f0 = __builtin_nontemporal_load(reinterpret_cast<const f32x4*>(&xt[(size_t)arow * FF + kb]));
                f32x4 f1 = __builtin_nontemporal_load(reinterpret_cast<const f32x4*>(&xt[(size_t)arow * FF + kb + 4]));
                au[s].h[0] = __float22bfloat162_rn(make_float2(f0[0], f0[1]));
                au[s].h[1] = __float22bfloat162_rn(make_float2(f0[2], f0[3]));
                au[s].h[2] = __float22bfloat162_rn(make_float2(f1[0], f1[1]));
                au[s].h[3] = __float22bfloat162_rn(make_float2(f1[2], f1[3]));
            } else {
                au[s].v = (bf16x8){0,0,0,0,0,0,0,0};
            }
        }
        #pragma unroll
        for (int n = 0; n < 4; ++n) {
            bf16x8 bf = *reinterpret_cast<const bf16x8*>(&wtt[(size_t)(n * 16 + l15) * FF + kb]);
            d[0][n] = __builtin_amdgcn_mfma_f32_16x16x32_bf16(au[0].v, bf, d[0][n], 0, 0, 0);
            d[1][n] = __builtin_amdgcn_mfma_f32_16x16x32_bf16(au[1].v, bf, d[1][n], 0, 0, 0);
        }
    }
    // scale by dinv, write column-fragments to LDS (cheap 2B LDS writes)
    #pragma unroll
    for (int s = 0; s < 2; ++s) {
        int rl = w * 32 + s * 16 + lg * 4;       // local row base of this lane's fragment
        float dv[4];
        #pragma unroll
        for (int i = 0; i < 4; ++i) {
            int grow = row0 + rl + i;
            dv[i] = (grow < NN) ? dinv[t * NN + grow] : 0.f;
        }
        #pragma unroll
        for (int n = 0; n < 4; ++n) {
            int col = n * 16 + l15;
            #pragma unroll
            for (int i = 0; i < 4; ++i)
                ylds[rl + i][col] = cvt_bf16(d[s][n][i] * dv[i]);
        }
    }
    __syncthreads();
    // coalesced dump: 256 rows x 128B = 2048 uint4; 4 per thread
    u16* yt = y + (size_t)t * NN * HH;
    #pragma unroll
    for (int it = 0; it < 4; ++it) {
        int idx = it * 512 + tid;
        int r = idx >> 3, c8 = (idx & 7) * 8;
        int grow = row0 + r;
        if (grow < NN)
            *reinterpret_cast<uint4*>(&yt[(size_t)grow * HH + c8]) =
                *reinterpret_cast<const uint4*>(&ylds[r][c8]);
    }
}

// ---------------- gather-aggregate over all T (single pass, full 128B rows) ----------------
// EXACT r8 structure (best measured: 177us @ 401MB compulsory floor, 2.39TB/s).
__global__ __launch_bounds__(256) void agg_kernel(const u16* __restrict__ y, const float* __restrict__ dinv,
                                                  const u32* __restrict__ nodeinfo, const u16* __restrict__ srclist,
                                                  const float* __restrict__ bg, float* __restrict__ acc) {
    int node = blockIdx.x * 4 + (threadIdx.x >> 6);
    int lane = threadIdx.x & 63;
    int sub = lane >> 4;            // edge slot 0..3
    int fo = lane & 15;             // feature quad: feats fo*4 .. fo*4+3
    float a0 = 0.f, a1 = 0.f, a2 = 0.f, a3 = 0.f;
    for (int t = 0; t < TT; ++t) {
        const u16* yt = y + (size_t)t * NN * HH;
        u32 info = nodeinfo[t * NN + node];
        int cnt = info >> 20;
        const u16* sl = srclist + (size_t)t * NB2 * CAP + (info & 0xFFFFF);
        float s0 = 0.f, s1 = 0.f, s2 = 0.f, s3 = 0.f;
        int j = 0;
        for (; j + 16 <= cnt; j += 16) {
            int e0 = sl[j + sub], e1 = sl[j + 4 + sub], e2 = sl[j + 8 + sub], e3 = sl[j + 12 + sub];
            uint2 v0 = *reinterpret_cast<const uint2*>(&yt[(size_t)e0 * HH + fo * 4]);
            uint2 v1 = *reinterpret_cast<const uint2*>(&yt[(size_t)e1 * HH + fo * 4]);
            uint2 v2 = *reinterpret_cast<const uint2*>(&yt[(size_t)e2 * HH + fo * 4]);
            uint2 v3 = *reinterpret_cast<const uint2*>(&yt[(size_t)e3 * HH + fo * 4]);
            s0 += (bflo(v0.x) + bflo(v1.x)) + (bflo(v2.x) + bflo(v3.x));
            s1 += (bfhi(v0.x) + bfhi(v1.x)) + (bfhi(v2.x) + bfhi(v3.x));
            s2 += (bflo(v0.y) + bflo(v1.y)) + (bflo(v2.y) + bflo(v3.y));
            s3 += (bfhi(v0.y) + bfhi(v1.y)) + (bfhi(v2.y) + bfhi(v3.y));
        }
        for (; j < cnt; j += 4) {
            int e = j + sub;
            uint2 v = make_uint2(0u, 0u);
            if (e < cnt) {
                int srcid = sl[e];
                v = *reinterpret_cast<const uint2*>(&yt[(size_t)srcid * HH + fo * 4]);
            }
            s0 += bflo(v.x);
            s1 += bfhi(v.x);
            s2 += bflo(v.y);
            s3 += bfhi(v.y);
        }
        s0 += __shfl_xor(s0, 16, 64); s0 += __shfl_xor(s0, 32, 64);
        s1 += __shfl_xor(s1, 16, 64); s1 += __shfl_xor(s1, 32, 64);
        s2 += __shfl_xor(s2, 16, 64); s2 += __shfl_xor(s2, 32, 64);
        s3 += __shfl_xor(s3, 16, 64); s3 += __shfl_xor(s3, 32, 64);
        // self loop (y already scaled by src dinv)
        uint2 sv = *reinterpret_cast<const uint2*>(&yt[(size_t)node * HH + fo * 4]);
        s0 += bflo(sv.x);
        s1 += bfhi(sv.x);
        s2 += bflo(sv.y);
        s3 += bfhi(sv.y);
        float dvv = dinv[t * NN + node];
        float4 bgv = *reinterpret_cast<const float4*>(&bg[t * HH + fo * 4]);
        a0 += fmaxf(dvv * s0 + bgv.x, 0.f);
        a1 += fmaxf(dvv * s1 + bgv.y, 0.f);
        a2 += fmaxf(dvv * s2 + bgv.z, 0.f);
        a3 += fmaxf(dvv * s3 + bgv.w, 0.f);
    }
    if (sub == 0) {
        float4 o = make_float4(a0, a1, a2, a3);
        *reinterpret_cast<float4*>(&acc[(size_t)node * HH + fo * 4]) = o;
    }
}

// ---------------- per-node MLP head + log_softmax ----------------
__global__ __launch_bounds__(256) void head_kernel(const float* __restrict__ acc,
                                                   const float* __restrict__ W1, const float* __restrict__ b1,
                                                   const float* __restrict__ W2, const float* __restrict__ b2,
                                                   const float* __restrict__ W3, const float* __restrict__ b3,
                                                   float* __restrict__ out) {
    __shared__ float w1[64 * 32], w2[32 * 16], w3[16 * 4], bb1[32], bb2[16], bb3[4];
    int tid = threadIdx.x;
    for (int i = tid; i < 2048; i += 256) w1[i] = W1[i];
    for (int i = tid; i < 512; i += 256) w2[i] = W2[i];
    if (tid < 64) w3[tid] = W3[tid];
    if (tid < 32) bb1[tid] = b1[tid];
    if (tid < 16) bb2[tid] = b2[tid];
    if (tid < 4) bb3[tid] = b3[tid];
    __syncthreads();
    int node = blockIdx.x * 256 + tid;
    if (node >= NN) return;

    float a[64];
    #pragma unroll
    for (int k = 0; k < 64; ++k) a[k] = acc[(size_t)node * HH + k];

    float h1[32];
    for (int j = 0; j < 32; ++j) {
        float s = bb1[j];
        #pragma unroll
        for (int k = 0; k < 64; ++k) s += a[k] * w1[k * 32 + j];
        h1[j] = fmaxf(s, 0.f);
    }
    float h2[16];
    for (int j = 0; j < 16; ++j) {
        float s = bb2[j];
        #pragma unroll
        for (int k = 0; k < 32; ++k) s += h1[k] * w2[k * 16 + j];
        h2[j] = fmaxf(s, 0.f);
    }
    float l[4];
    for (int c = 0; c < 4; ++c) {
        float s = bb3[c];
        #pragma unroll
        for (int k = 0; k < 16; ++k) s += h2[k] * w3[k * 4 + c];
        l[c] = s;
    }
    float m = fmaxf(fmaxf(l[0], l[1]), fmaxf(l[2], l[3]));
    float sum = 0.f;
    #pragma unroll
    for (int c = 0; c < 4; ++c) sum += expf(l[c] - m);
    float lse = logf(sum);
    float4 o;
    o.x = l[0] - m - lse; o.y = l[1] - m - lse; o.z = l[2] - m - lse; o.w = l[3] - m - lse;
    *reinterpret_cast<float4*>(&out[(size_t)node * CC]) = o;
}

extern "C" void kernel_launch(void* const* d_in, const int* in_sizes, int n_in,
                              void* d_out, int out_size, void* d_ws, size_t ws_size,
                              hipStream_t stream) {
    const float* x    = (const float*)d_in[0];
    const int*  edges = (const int*)d_in[1];
    const float* Wg   = (const float*)d_in[2];
    const float* bg   = (const float*)d_in[3];
    const float* W1   = (const float*)d_in[4];
    const float* b1   = (const float*)d_in[5];
    const float* W2   = (const float*)d_in[6];
    const float* b2   = (const float*)d_in[7];
    const float* W3   = (const float*)d_in[8];
    const float* b3   = (const float*)d_in[9];
    float* out = (float*)d_out;

    char* ws = (char*)d_ws;
    size_t o = 0;
    int* gcur      = (int*)(ws + o); o += (size_t)TT * NB2 * 4;            // 12.5 KB
    o = (o + 255) & ~(size_t)255;
    float* dinv    = (float*)(ws + o); o += (size_t)TT * NN * 4;           // 1.6 MB
    u32* nodeinfo  = (u32*)(ws + o); o += (size_t)TT * NN * 4;             // 1.6 MB
    o = (o + 255) & ~(size_t)255;
    u16* wt        = (u16*)(ws + o); o += (size_t)TT * HH * FF * 2;        // 128 KB
    o = (o + 255) & ~(size_t)255;
    u32* binned    = (u32*)(ws + o); o += (size_t)TT * NB2 * CAP * 4;      // 32.0 MB
    u16* srclist   = (u16*)(ws + o); o += (size_t)TT * NB2 * CAP * 2;      // 16.0 MB
    u16* y         = (u16*)(ws + o); o += (size_t)TT * NN * HH * 2;        // 51.2 MB
    float* acc     = (float*)(ws + o); o += (size_t)NN * HH * 4;           // 12.8 MB
    // total ~115 MB

    zero_gcur_kernel<<<(TT * NB2 + 255) / 256, 256, 0, stream>>>(gcur);

    multisplit_kernel<<<BPT * TT, 256, 0, stream>>>(edges, gcur, binned);

    dim3 gsc(NB2, TT);
    csr_scatter_kernel<<<gsc, 512, 0, stream>>>(binned, gcur, srclist, nodeinfo, dinv);

    wt_prep_kernel<<<TT, 256, 0, stream>>>(Wg, wt);

    dim3 gx(196, TT);
    xw_kernel<<<gx, 512, 0, stream>>>(x, wt, dinv, y);

    agg_kernel<<<12500, 256, 0, stream>>>(y, dinv, nodeinfo, srclist, bg, acc);

    head_kernel<<<196, 256, 0, stream>>>(acc, W1, b1, W2, b2, W3, b3, out);
}